// Round 1
// baseline (485.730 us; speedup 1.0000x reference)
//
#include <hip/hip_runtime.h>
#include <math.h>

#define Bc 2
#define Cc 320
#define Pc 2304
#define HEADSc 8
#define DHc 64
#define INNERc 512
#define Fc 32
#define LN_EPS 1e-5f

// ---------------------------------------------------------------------------
// 1. LayerNorm over channel dim of ehs [B, C, P] -> ehs_ln [B, C, P]
//    block = 256 threads = 64 positions x 4 channel-groups (80 ch each)
// ---------------------------------------------------------------------------
__global__ __launch_bounds__(256) void ln_kernel(
    const float* __restrict__ ehs, const float* __restrict__ gamma,
    const float* __restrict__ beta, float* __restrict__ out) {
  int lane = threadIdx.x & 63, g = threadIdx.x >> 6;
  int gp = blockIdx.x * 64 + lane;           // global position in [0, B*P)
  int b = gp / Pc, p = gp % Pc;
  const float* base = ehs + (size_t)b * Cc * Pc + p;

  float sum = 0.f, sumsq = 0.f;
  for (int c = g * 80; c < (g + 1) * 80; ++c) {
    float x = base[(size_t)c * Pc];
    sum += x; sumsq += x * x;
  }
  __shared__ float s1[4][64], s2[4][64];
  __shared__ float mrs[64][2];
  s1[g][lane] = sum; s2[g][lane] = sumsq;
  __syncthreads();
  if (threadIdx.x < 64) {
    int l = threadIdx.x;
    float ts = s1[0][l] + s1[1][l] + s1[2][l] + s1[3][l];
    float tq = s2[0][l] + s2[1][l] + s2[2][l] + s2[3][l];
    float mean = ts / (float)Cc;
    float var = tq / (float)Cc - mean * mean;
    mrs[l][0] = mean;
    mrs[l][1] = rsqrtf(var + LN_EPS);
  }
  __syncthreads();
  float mean = mrs[lane][0], rstd = mrs[lane][1];
  float* ob = out + (size_t)b * Cc * Pc + p;
  for (int c = g * 80; c < (g + 1) * 80; ++c) {
    float x = base[(size_t)c * Pc];
    ob[(size_t)c * Pc] = (x - mean) * rstd * gamma[c] + beta[c];
  }
}

// ---------------------------------------------------------------------------
// 2. GEMM (A^T form): Out[b][n][pos] = sum_c A[b][c][pos] * W[c][n]
//    A: [B, K, P], W: [K, N], Out: [B, N, P]
//    64x64 tile, 256 threads, 4x4 micro-tile, K-chunks of 16.
// ---------------------------------------------------------------------------
__global__ __launch_bounds__(256) void gemm_at_kernel(
    const float* __restrict__ A, const float* __restrict__ W,
    float* __restrict__ Out, int K, int N) {
  __shared__ float As[16][64];
  __shared__ float Ws[16][64];
  int b = blockIdx.z;
  const float* Ab = A + (size_t)b * K * Pc;
  float* Ob = Out + (size_t)b * N * Pc;
  int pos0 = blockIdx.x * 64, n0 = blockIdx.y * 64;
  int tid = threadIdx.x;
  int tx = tid & 15, ty = tid >> 4;

  float acc[4][4] = {};
  for (int k0 = 0; k0 < K; k0 += 16) {
    for (int l = tid; l < 1024; l += 256) {
      int kk = l >> 6, pp = l & 63;
      As[kk][pp] = Ab[(size_t)(k0 + kk) * Pc + pos0 + pp];
      Ws[kk][pp] = W[(size_t)(k0 + kk) * N + n0 + pp];
    }
    __syncthreads();
#pragma unroll
    for (int kk = 0; kk < 16; ++kk) {
      float4 av = *reinterpret_cast<const float4*>(&As[kk][tx * 4]);
      float4 bv = *reinterpret_cast<const float4*>(&Ws[kk][ty * 4]);
      float a[4] = {av.x, av.y, av.z, av.w};
      float bb[4] = {bv.x, bv.y, bv.z, bv.w};
#pragma unroll
      for (int i = 0; i < 4; ++i)
#pragma unroll
        for (int j = 0; j < 4; ++j) acc[i][j] += a[i] * bb[j];
    }
    __syncthreads();
  }
#pragma unroll
  for (int j = 0; j < 4; ++j) {
    int n = n0 + ty * 4 + j;
    float4 o = make_float4(acc[0][j], acc[1][j], acc[2][j], acc[3][j]);
    *reinterpret_cast<float4*>(&Ob[(size_t)n * Pc + pos0 + tx * 4]) = o;
  }
}

// ---------------------------------------------------------------------------
// 3/5. Logits: L[b][h][f][pos] = s * sum_d filt[f][h*64+d] * Xt[b][h*64+d][pos]
//    grid (P/256, H, B), block 256 (one pos per thread)
// ---------------------------------------------------------------------------
__global__ __launch_bounds__(256) void logits_kernel(
    const float* __restrict__ Xt, const float* __restrict__ filt,
    const float* __restrict__ scale_p, float* __restrict__ L) {
  int b = blockIdx.z, h = blockIdx.y;
  int pos = blockIdx.x * 256 + threadIdx.x;
  __shared__ float flds[Fc][DHc];
  for (int l = threadIdx.x; l < Fc * DHc; l += 256) {
    int f = l >> 6, d = l & 63;
    flds[f][d] = filt[(size_t)f * INNERc + h * DHc + d];
  }
  __syncthreads();
  float s = scale_p[0];
  float kv[DHc];
  const float* xb = Xt + ((size_t)b * INNERc + h * DHc) * Pc + pos;
#pragma unroll
  for (int d = 0; d < DHc; ++d) kv[d] = xb[(size_t)d * Pc];
  float* Lb = L + ((size_t)(b * HEADSc + h) * Fc) * Pc + pos;
  for (int f = 0; f < Fc; ++f) {
    float acc = 0.f;
#pragma unroll
    for (int d = 0; d < DHc; ++d) acc += flds[f][d] * kv[d];
    Lb[(size_t)f * Pc] = acc * s;
  }
}

// ---------------------------------------------------------------------------
// 4. Softmax along pos (row length P) for each row of L [B*H*F, P]
// ---------------------------------------------------------------------------
__global__ __launch_bounds__(256) void softmax_rows_kernel(float* __restrict__ L) {
  __shared__ float red[4];
  float* Lr = L + (size_t)blockIdx.x * Pc;
  int tid = threadIdx.x, lane = tid & 63, wv = tid >> 6;
  float vals[9];
  float m = -1e30f;
#pragma unroll
  for (int i = 0; i < 9; ++i) {
    vals[i] = Lr[tid + 256 * i];
    m = fmaxf(m, vals[i]);
  }
#pragma unroll
  for (int o = 32; o > 0; o >>= 1) m = fmaxf(m, __shfl_xor(m, o));
  if (lane == 0) red[wv] = m;
  __syncthreads();
  m = fmaxf(fmaxf(red[0], red[1]), fmaxf(red[2], red[3]));
  __syncthreads();
  float sum = 0.f;
#pragma unroll
  for (int i = 0; i < 9; ++i) {
    vals[i] = __expf(vals[i] - m);
    sum += vals[i];
  }
#pragma unroll
  for (int o = 32; o > 0; o >>= 1) sum += __shfl_xor(sum, o);
  if (lane == 0) red[wv] = sum;
  __syncthreads();
  sum = red[0] + red[1] + red[2] + red[3];
  float inv = 1.f / sum;
#pragma unroll
  for (int i = 0; i < 9; ++i) Lr[tid + 256 * i] = vals[i] * inv;
}

// ---------------------------------------------------------------------------
// 6. Softmax along f (32) for each (b,h,pos): L [B,H,F,P], stride P between f
// ---------------------------------------------------------------------------
__global__ __launch_bounds__(256) void softmax_f_kernel(float* __restrict__ L) {
  int b = blockIdx.z, h = blockIdx.y;
  int pos = blockIdx.x * 256 + threadIdx.x;
  float* Lb = L + ((size_t)(b * HEADSc + h) * Fc) * Pc + pos;
  float v[Fc];
  float m = -1e30f;
#pragma unroll
  for (int f = 0; f < Fc; ++f) {
    v[f] = Lb[(size_t)f * Pc];
    m = fmaxf(m, v[f]);
  }
  float sum = 0.f;
#pragma unroll
  for (int f = 0; f < Fc; ++f) {
    v[f] = __expf(v[f] - m);
    sum += v[f];
  }
  float inv = 1.f / sum;
#pragma unroll
  for (int f = 0; f < Fc; ++f) Lb[(size_t)f * Pc] = v[f] * inv;
}

// ---------------------------------------------------------------------------
// 7. sv[b][h][f][d] = sum_pos spatial[b][h][f][pos] * Vt[b][h*64+d][pos]
//    grid (F, H, B), block 256 = 4 waves; wave w covers d in [16w, 16w+16)
// ---------------------------------------------------------------------------
__global__ __launch_bounds__(256) void sv_kernel(
    const float* __restrict__ spatial, const float* __restrict__ Vt,
    float* __restrict__ sv) {
  int b = blockIdx.z, h = blockIdx.y, f = blockIdx.x;
  int lane = threadIdx.x & 63, wv = threadIdx.x >> 6;
  const float* sp = spatial + (((size_t)(b * HEADSc + h)) * Fc + f) * Pc;
  const float* vb = Vt + ((size_t)b * INNERc + h * DHc) * Pc;
  for (int dd = 0; dd < 16; ++dd) {
    int d = wv * 16 + dd;
    float acc = 0.f;
    for (int p = lane; p < Pc; p += 64)
      acc += sp[p] * vb[(size_t)d * Pc + p];
#pragma unroll
    for (int o = 32; o > 0; o >>= 1) acc += __shfl_down(acc, o);
    if (lane == 0)
      sv[(((size_t)(b * HEADSc + h)) * Fc + f) * DHc + d] = acc;
  }
}

// ---------------------------------------------------------------------------
// 8. OA[b][h*64+d][pos] = sum_f channel[b][h][f][pos] * sv[b][h][f][d]
//    grid (P/64, H, B), block 256 = 4 waves; wave w covers 16 d's, lanes = pos
// ---------------------------------------------------------------------------
__global__ __launch_bounds__(256) void oa_kernel(
    const float* __restrict__ channel, const float* __restrict__ sv,
    float* __restrict__ OA) {
  int b = blockIdx.z, h = blockIdx.y;
  int lane = threadIdx.x & 63, wv = threadIdx.x >> 6;
  int pos = blockIdx.x * 64 + lane;
  __shared__ float svl[Fc][DHc];
  for (int l = threadIdx.x; l < Fc * DHc; l += 256)
    svl[l >> 6][l & 63] = sv[((size_t)(b * HEADSc + h)) * Fc * DHc + l];
  __syncthreads();
  const float* ch = channel + (((size_t)(b * HEADSc + h)) * Fc) * Pc + pos;
  float acc[16] = {};
  for (int f = 0; f < Fc; ++f) {
    float cf = ch[(size_t)f * Pc];
#pragma unroll
    for (int dd = 0; dd < 16; ++dd) acc[dd] += cf * svl[f][wv * 16 + dd];
  }
  float* ob = OA + ((size_t)b * INNERc + h * DHc + wv * 16) * Pc + pos;
#pragma unroll
  for (int dd = 0; dd < 16; ++dd) ob[(size_t)dd * Pc] = acc[dd];
}

// ---------------------------------------------------------------------------
// 9. Final GEMM + epilogue:
//    out[b][c][pos] = sum_i OA[b][i][pos]*Wo[i][c] + bo[c] + s*res[b][c][pos]
// ---------------------------------------------------------------------------
__global__ __launch_bounds__(256) void final_gemm_kernel(
    const float* __restrict__ OA, const float* __restrict__ Wo,
    const float* __restrict__ bo, const float* __restrict__ res,
    const float* __restrict__ scale_p, float* __restrict__ out) {
  __shared__ float As[16][64];
  __shared__ float Ws[16][64];
  int b = blockIdx.z;
  const float* Ab = OA + (size_t)b * INNERc * Pc;
  int pos0 = blockIdx.x * 64, n0 = blockIdx.y * 64;
  int tid = threadIdx.x;
  int tx = tid & 15, ty = tid >> 4;

  float acc[4][4] = {};
  for (int k0 = 0; k0 < INNERc; k0 += 16) {
    for (int l = tid; l < 1024; l += 256) {
      int kk = l >> 6, pp = l & 63;
      As[kk][pp] = Ab[(size_t)(k0 + kk) * Pc + pos0 + pp];
      Ws[kk][pp] = Wo[(size_t)(k0 + kk) * Cc + n0 + pp];
    }
    __syncthreads();
#pragma unroll
    for (int kk = 0; kk < 16; ++kk) {
      float4 av = *reinterpret_cast<const float4*>(&As[kk][tx * 4]);
      float4 bv = *reinterpret_cast<const float4*>(&Ws[kk][ty * 4]);
      float a[4] = {av.x, av.y, av.z, av.w};
      float bb[4] = {bv.x, bv.y, bv.z, bv.w};
#pragma unroll
      for (int i = 0; i < 4; ++i)
#pragma unroll
        for (int j = 0; j < 4; ++j) acc[i][j] += a[i] * bb[j];
    }
    __syncthreads();
  }
  float s = scale_p[0];
#pragma unroll
  for (int j = 0; j < 4; ++j) {
    int n = n0 + ty * 4 + j;
    float bias = bo[n];
    const float4 r = *reinterpret_cast<const float4*>(
        &res[((size_t)b * Cc + n) * Pc + pos0 + tx * 4]);
    float4 o;
    o.x = acc[0][j] + bias + r.x * s;
    o.y = acc[1][j] + bias + r.y * s;
    o.z = acc[2][j] + bias + r.z * s;
    o.w = acc[3][j] + bias + r.w * s;
    *reinterpret_cast<float4*>(
        &out[((size_t)b * Cc + n) * Pc + pos0 + tx * 4]) = o;
  }
}

// ---------------------------------------------------------------------------
extern "C" void kernel_launch(void* const* d_in, const int* in_sizes, int n_in,
                              void* d_out, int out_size, void* d_ws, size_t ws_size,
                              hipStream_t stream) {
  const float* hs    = (const float*)d_in[0];   // hidden_states [B,C,P]
  const float* ehs   = (const float*)d_in[1];   // encoder_hidden_states [B,C,P]
  const float* Wq    = (const float*)d_in[2];   // [C, INNER]
  const float* Wk    = (const float*)d_in[3];
  const float* Wv    = (const float*)d_in[4];
  const float* Wo    = (const float*)d_in[5];   // [INNER, C]
  const float* bo    = (const float*)d_in[6];   // [C]
  const float* gamma = (const float*)d_in[7];
  const float* beta  = (const float*)d_in[8];
  const float* exf   = (const float*)d_in[9];   // [F, INNER]
  const float* dif   = (const float*)d_in[10];  // [F, INNER]
  const float* scale = (const float*)d_in[11];  // [1]
  float* out = (float*)d_out;

  float* ws = (float*)d_ws;
  const size_t SZ_CP = (size_t)Bc * Cc * Pc;       // 1,474,560
  const size_t SZ_IP = (size_t)Bc * INNERc * Pc;   // 2,359,296
  const size_t SZ_L  = (size_t)Bc * HEADSc * Fc * Pc; // 1,179,648
  float* ehs_ln = ws;                  // [B,C,P]
  float* Qt = ehs_ln + SZ_CP;          // [B,INNER,P]
  float* Kt = Qt + SZ_IP;
  float* Vt = Kt + SZ_IP;
  float* L1 = Vt + SZ_IP;              // spatial logits/probs [B,H,F,P]
  float* Lc = L1 + SZ_L;               // channel logits/probs [B,H,F,P]
  float* sv = Lc + SZ_L;               // [B,H,F,DH]
  float* OA = sv + (size_t)Bc * HEADSc * Fc * DHc;  // [B,INNER,P]

  // 1. LayerNorm
  ln_kernel<<<dim3((Bc * Pc) / 64), dim3(256), 0, stream>>>(ehs, gamma, beta, ehs_ln);
  // 2. Projections
  gemm_at_kernel<<<dim3(Pc / 64, INNERc / 64, Bc), dim3(256), 0, stream>>>(hs, Wq, Qt, Cc, INNERc);
  gemm_at_kernel<<<dim3(Pc / 64, INNERc / 64, Bc), dim3(256), 0, stream>>>(ehs_ln, Wk, Kt, Cc, INNERc);
  gemm_at_kernel<<<dim3(Pc / 64, INNERc / 64, Bc), dim3(256), 0, stream>>>(ehs_ln, Wv, Vt, Cc, INNERc);
  // 3. Spatial logits + softmax over pos
  logits_kernel<<<dim3(Pc / 256, HEADSc, Bc), dim3(256), 0, stream>>>(Kt, exf, scale, L1);
  softmax_rows_kernel<<<dim3(Bc * HEADSc * Fc), dim3(256), 0, stream>>>(L1);
  // 4. Channel logits + softmax over f
  logits_kernel<<<dim3(Pc / 256, HEADSc, Bc), dim3(256), 0, stream>>>(Qt, dif, scale, Lc);
  softmax_f_kernel<<<dim3(Pc / 256, HEADSc, Bc), dim3(256), 0, stream>>>(Lc);
  // 5. sv = spatial @ V
  sv_kernel<<<dim3(Fc, HEADSc, Bc), dim3(256), 0, stream>>>(L1, Vt, sv);
  // 6. OA = channel^T @ sv
  oa_kernel<<<dim3(Pc / 64, HEADSc, Bc), dim3(256), 0, stream>>>(Lc, sv, OA);
  // 7. Output projection + bias + scaled residual
  final_gemm_kernel<<<dim3(Pc / 64, Cc / 64, Bc), dim3(256), 0, stream>>>(OA, Wo, bo, hs, scale, out);
}

// Round 2
// 329.534 us; speedup vs baseline: 1.4740x; 1.4740x over previous
//
#include <hip/hip_runtime.h>
#include <math.h>

#define Bc 2
#define Cc 320
#define Pc 2304
#define HEADSc 8
#define DHc 64
#define INNERc 512
#define Fc 32
#define LN_EPS 1e-5f
#define CHUNKS 18
#define CHUNK_P (Pc / CHUNKS)  // 128

// ---------------------------------------------------------------------------
// 1. LayerNorm over channel dim of ehs [B, C, P] -> ehs_ln [B, C, P]
// ---------------------------------------------------------------------------
__global__ __launch_bounds__(256) void ln_kernel(
    const float* __restrict__ ehs, const float* __restrict__ gamma,
    const float* __restrict__ beta, float* __restrict__ out) {
  int lane = threadIdx.x & 63, g = threadIdx.x >> 6;
  int gp = blockIdx.x * 64 + lane;           // global position in [0, B*P)
  int b = gp / Pc, p = gp % Pc;
  const float* base = ehs + (size_t)b * Cc * Pc + p;

  float sum = 0.f, sumsq = 0.f;
  for (int c = g * 80; c < (g + 1) * 80; ++c) {
    float x = base[(size_t)c * Pc];
    sum += x; sumsq += x * x;
  }
  __shared__ float s1[4][64], s2[4][64];
  __shared__ float mrs[64][2];
  s1[g][lane] = sum; s2[g][lane] = sumsq;
  __syncthreads();
  if (threadIdx.x < 64) {
    int l = threadIdx.x;
    float ts = s1[0][l] + s1[1][l] + s1[2][l] + s1[3][l];
    float tq = s2[0][l] + s2[1][l] + s2[2][l] + s2[3][l];
    float mean = ts / (float)Cc;
    float var = tq / (float)Cc - mean * mean;
    mrs[l][0] = mean;
    mrs[l][1] = rsqrtf(var + LN_EPS);
  }
  __syncthreads();
  float mean = mrs[lane][0], rstd = mrs[lane][1];
  float* ob = out + (size_t)b * Cc * Pc + p;
  for (int c = g * 80; c < (g + 1) * 80; ++c) {
    float x = base[(size_t)c * Pc];
    ob[(size_t)c * Pc] = (x - mean) * rstd * gamma[c] + beta[c];
  }
}

// ---------------------------------------------------------------------------
// 2. GEMM (A^T form): Out[b][n][pos] = sum_c A[b][c][pos] * W[c][n]
// ---------------------------------------------------------------------------
__global__ __launch_bounds__(256) void gemm_at_kernel(
    const float* __restrict__ A, const float* __restrict__ W,
    float* __restrict__ Out, int K, int N) {
  __shared__ float As[16][64];
  __shared__ float Ws[16][64];
  int b = blockIdx.z;
  const float* Ab = A + (size_t)b * K * Pc;
  float* Ob = Out + (size_t)b * N * Pc;
  int pos0 = blockIdx.x * 64, n0 = blockIdx.y * 64;
  int tid = threadIdx.x;
  int tx = tid & 15, ty = tid >> 4;

  float acc[4][4] = {};
  for (int k0 = 0; k0 < K; k0 += 16) {
    for (int l = tid; l < 1024; l += 256) {
      int kk = l >> 6, pp = l & 63;
      As[kk][pp] = Ab[(size_t)(k0 + kk) * Pc + pos0 + pp];
      Ws[kk][pp] = W[(size_t)(k0 + kk) * N + n0 + pp];
    }
    __syncthreads();
#pragma unroll
    for (int kk = 0; kk < 16; ++kk) {
      float4 av = *reinterpret_cast<const float4*>(&As[kk][tx * 4]);
      float4 bv = *reinterpret_cast<const float4*>(&Ws[kk][ty * 4]);
      float a[4] = {av.x, av.y, av.z, av.w};
      float bb[4] = {bv.x, bv.y, bv.z, bv.w};
#pragma unroll
      for (int i = 0; i < 4; ++i)
#pragma unroll
        for (int j = 0; j < 4; ++j) acc[i][j] += a[i] * bb[j];
    }
    __syncthreads();
  }
#pragma unroll
  for (int j = 0; j < 4; ++j) {
    int n = n0 + ty * 4 + j;
    float4 o = make_float4(acc[0][j], acc[1][j], acc[2][j], acc[3][j]);
    *reinterpret_cast<float4*>(&Ob[(size_t)n * Pc + pos0 + tx * 4]) = o;
  }
}

// ---------------------------------------------------------------------------
// 3/5. Logits: L[b][h][f][pos] = s * sum_d filt[f][h*64+d] * Xt[b][h*64+d][pos]
// ---------------------------------------------------------------------------
__global__ __launch_bounds__(256) void logits_kernel(
    const float* __restrict__ Xt, const float* __restrict__ filt,
    const float* __restrict__ scale_p, float* __restrict__ L) {
  int b = blockIdx.z, h = blockIdx.y;
  int pos = blockIdx.x * 256 + threadIdx.x;
  __shared__ float flds[Fc][DHc];
  for (int l = threadIdx.x; l < Fc * DHc; l += 256) {
    int f = l >> 6, d = l & 63;
    flds[f][d] = filt[(size_t)f * INNERc + h * DHc + d];
  }
  __syncthreads();
  float s = scale_p[0];
  float kv[DHc];
  const float* xb = Xt + ((size_t)b * INNERc + h * DHc) * Pc + pos;
#pragma unroll
  for (int d = 0; d < DHc; ++d) kv[d] = xb[(size_t)d * Pc];
  float* Lb = L + ((size_t)(b * HEADSc + h) * Fc) * Pc + pos;
  for (int f = 0; f < Fc; ++f) {
    float acc = 0.f;
#pragma unroll
    for (int d = 0; d < DHc; ++d) acc += flds[f][d] * kv[d];
    Lb[(size_t)f * Pc] = acc * s;
  }
}

// ---------------------------------------------------------------------------
// 4. Softmax along pos (row length P) for each row of L [B*H*F, P]
// ---------------------------------------------------------------------------
__global__ __launch_bounds__(256) void softmax_rows_kernel(float* __restrict__ L) {
  __shared__ float red[4];
  float* Lr = L + (size_t)blockIdx.x * Pc;
  int tid = threadIdx.x, lane = tid & 63, wv = tid >> 6;
  float vals[9];
  float m = -1e30f;
#pragma unroll
  for (int i = 0; i < 9; ++i) {
    vals[i] = Lr[tid + 256 * i];
    m = fmaxf(m, vals[i]);
  }
#pragma unroll
  for (int o = 32; o > 0; o >>= 1) m = fmaxf(m, __shfl_xor(m, o));
  if (lane == 0) red[wv] = m;
  __syncthreads();
  m = fmaxf(fmaxf(red[0], red[1]), fmaxf(red[2], red[3]));
  __syncthreads();
  float sum = 0.f;
#pragma unroll
  for (int i = 0; i < 9; ++i) {
    vals[i] = __expf(vals[i] - m);
    sum += vals[i];
  }
#pragma unroll
  for (int o = 32; o > 0; o >>= 1) sum += __shfl_xor(sum, o);
  if (lane == 0) red[wv] = sum;
  __syncthreads();
  sum = red[0] + red[1] + red[2] + red[3];
  float inv = 1.f / sum;
#pragma unroll
  for (int i = 0; i < 9; ++i) Lr[tid + 256 * i] = vals[i] * inv;
}

// ---------------------------------------------------------------------------
// 6. Softmax along f (32) for each (b,h,pos)
// ---------------------------------------------------------------------------
__global__ __launch_bounds__(256) void softmax_f_kernel(float* __restrict__ L) {
  int b = blockIdx.z, h = blockIdx.y;
  int pos = blockIdx.x * 256 + threadIdx.x;
  float* Lb = L + ((size_t)(b * HEADSc + h) * Fc) * Pc + pos;
  float v[Fc];
  float m = -1e30f;
#pragma unroll
  for (int f = 0; f < Fc; ++f) {
    v[f] = Lb[(size_t)f * Pc];
    m = fmaxf(m, v[f]);
  }
  float sum = 0.f;
#pragma unroll
  for (int f = 0; f < Fc; ++f) {
    v[f] = __expf(v[f] - m);
    sum += v[f];
  }
  float inv = 1.f / sum;
#pragma unroll
  for (int f = 0; f < Fc; ++f) Lb[(size_t)f * Pc] = v[f] * inv;
}

// ---------------------------------------------------------------------------
// 7a. sv partials: GEMM M=32(F) N=64(DH) K=P, split-K over 18 chunks of 128.
//     grid (18, H, B), block 256. LDS tiles stored contraction-major
//     ([pp][f], [pp][d]) so the inner loop does float2/float4 LDS reads.
//     svp layout: [chunk][bh][f][d]
// ---------------------------------------------------------------------------
__global__ __launch_bounds__(256) void sv_part_kernel(
    const float* __restrict__ spatial, const float* __restrict__ Vt,
    float* __restrict__ svp) {
  int b = blockIdx.z, h = blockIdx.y, c = blockIdx.x;
  int tid = threadIdx.x;
  int tx = tid & 15, ty = tid >> 4;   // tx -> d-quad, ty -> f-pair
  int p0base = c * CHUNK_P;
  const float* sp = spatial + ((size_t)(b * HEADSc + h)) * Fc * Pc;
  const float* vb = Vt + ((size_t)b * INNERc + h * DHc) * Pc;

  __shared__ float sp_s[64][34];  // [pp][f], pad->conflict-free writes
  __shared__ float v_s[64][68];   // [pp][d], pad 68 keeps 16B-aligned rows

  float acc[2][4] = {};
  for (int t = 0; t < CHUNK_P; t += 64) {
    int p0 = p0base + t;
    for (int l = tid; l < Fc * 64; l += 256) {       // 2048 elems
      int f = l >> 6, pp = l & 63;
      sp_s[pp][f] = sp[(size_t)f * Pc + p0 + pp];
    }
    for (int l = tid; l < DHc * 64; l += 256) {      // 4096 elems
      int d = l >> 6, pp = l & 63;
      v_s[pp][d] = vb[(size_t)d * Pc + p0 + pp];
    }
    __syncthreads();
#pragma unroll
    for (int kk = 0; kk < 64; ++kk) {
      float2 a = *reinterpret_cast<const float2*>(&sp_s[kk][ty * 2]);
      float4 bv = *reinterpret_cast<const float4*>(&v_s[kk][tx * 4]);
      acc[0][0] += a.x * bv.x; acc[0][1] += a.x * bv.y;
      acc[0][2] += a.x * bv.z; acc[0][3] += a.x * bv.w;
      acc[1][0] += a.y * bv.x; acc[1][1] += a.y * bv.y;
      acc[1][2] += a.y * bv.z; acc[1][3] += a.y * bv.w;
    }
    __syncthreads();
  }
  int bh = b * HEADSc + h;
  float* op = svp + ((size_t)c * 16 + bh) * (Fc * DHc);
#pragma unroll
  for (int i = 0; i < 2; ++i) {
    int f = ty * 2 + i;
    *reinterpret_cast<float4*>(&op[(size_t)f * DHc + tx * 4]) =
        make_float4(acc[i][0], acc[i][1], acc[i][2], acc[i][3]);
  }
}

// ---------------------------------------------------------------------------
// 7b. reduce the 18 split-K partials: sv[bh][f][d] = sum_c svp[c][bh][f][d]
// ---------------------------------------------------------------------------
__global__ __launch_bounds__(256) void sv_reduce_kernel(
    const float* __restrict__ svp, float* __restrict__ sv) {
  int idx = blockIdx.x * 256 + threadIdx.x;  // over 16*32*64 = 32768
  float s = 0.f;
#pragma unroll
  for (int c = 0; c < CHUNKS; ++c) s += svp[(size_t)c * 32768 + idx];
  sv[idx] = s;
}

// ---------------------------------------------------------------------------
// 8. OA[b][h*64+d][pos] = sum_f channel[b][h][f][pos] * sv[b][h][f][d]
// ---------------------------------------------------------------------------
__global__ __launch_bounds__(256) void oa_kernel(
    const float* __restrict__ channel, const float* __restrict__ sv,
    float* __restrict__ OA) {
  int b = blockIdx.z, h = blockIdx.y;
  int lane = threadIdx.x & 63, wv = threadIdx.x >> 6;
  int pos = blockIdx.x * 64 + lane;
  __shared__ float svl[Fc][DHc];
  for (int l = threadIdx.x; l < Fc * DHc; l += 256)
    svl[l >> 6][l & 63] = sv[((size_t)(b * HEADSc + h)) * Fc * DHc + l];
  __syncthreads();
  const float* ch = channel + (((size_t)(b * HEADSc + h)) * Fc) * Pc + pos;
  float acc[16] = {};
  for (int f = 0; f < Fc; ++f) {
    float cf = ch[(size_t)f * Pc];
#pragma unroll
    for (int dd = 0; dd < 16; ++dd) acc[dd] += cf * svl[f][wv * 16 + dd];
  }
  float* ob = OA + ((size_t)b * INNERc + h * DHc + wv * 16) * Pc + pos;
#pragma unroll
  for (int dd = 0; dd < 16; ++dd) ob[(size_t)dd * Pc] = acc[dd];
}

// ---------------------------------------------------------------------------
// 9. Final GEMM + epilogue
// ---------------------------------------------------------------------------
__global__ __launch_bounds__(256) void final_gemm_kernel(
    const float* __restrict__ OA, const float* __restrict__ Wo,
    const float* __restrict__ bo, const float* __restrict__ res,
    const float* __restrict__ scale_p, float* __restrict__ out) {
  __shared__ float As[16][64];
  __shared__ float Ws[16][64];
  int b = blockIdx.z;
  const float* Ab = OA + (size_t)b * INNERc * Pc;
  int pos0 = blockIdx.x * 64, n0 = blockIdx.y * 64;
  int tid = threadIdx.x;
  int tx = tid & 15, ty = tid >> 4;

  float acc[4][4] = {};
  for (int k0 = 0; k0 < INNERc; k0 += 16) {
    for (int l = tid; l < 1024; l += 256) {
      int kk = l >> 6, pp = l & 63;
      As[kk][pp] = Ab[(size_t)(k0 + kk) * Pc + pos0 + pp];
      Ws[kk][pp] = Wo[(size_t)(k0 + kk) * Cc + n0 + pp];
    }
    __syncthreads();
#pragma unroll
    for (int kk = 0; kk < 16; ++kk) {
      float4 av = *reinterpret_cast<const float4*>(&As[kk][tx * 4]);
      float4 bv = *reinterpret_cast<const float4*>(&Ws[kk][ty * 4]);
      float a[4] = {av.x, av.y, av.z, av.w};
      float bb[4] = {bv.x, bv.y, bv.z, bv.w};
#pragma unroll
      for (int i = 0; i < 4; ++i)
#pragma unroll
        for (int j = 0; j < 4; ++j) acc[i][j] += a[i] * bb[j];
    }
    __syncthreads();
  }
  float s = scale_p[0];
#pragma unroll
  for (int j = 0; j < 4; ++j) {
    int n = n0 + ty * 4 + j;
    float bias = bo[n];
    const float4 r = *reinterpret_cast<const float4*>(
        &res[((size_t)b * Cc + n) * Pc + pos0 + tx * 4]);
    float4 o;
    o.x = acc[0][j] + bias + r.x * s;
    o.y = acc[1][j] + bias + r.y * s;
    o.z = acc[2][j] + bias + r.z * s;
    o.w = acc[3][j] + bias + r.w * s;
    *reinterpret_cast<float4*>(
        &out[((size_t)b * Cc + n) * Pc + pos0 + tx * 4]) = o;
  }
}

// ---------------------------------------------------------------------------
extern "C" void kernel_launch(void* const* d_in, const int* in_sizes, int n_in,
                              void* d_out, int out_size, void* d_ws, size_t ws_size,
                              hipStream_t stream) {
  const float* hs    = (const float*)d_in[0];
  const float* ehs   = (const float*)d_in[1];
  const float* Wq    = (const float*)d_in[2];
  const float* Wk    = (const float*)d_in[3];
  const float* Wv    = (const float*)d_in[4];
  const float* Wo    = (const float*)d_in[5];
  const float* bo    = (const float*)d_in[6];
  const float* gamma = (const float*)d_in[7];
  const float* beta  = (const float*)d_in[8];
  const float* exf   = (const float*)d_in[9];
  const float* dif   = (const float*)d_in[10];
  const float* scale = (const float*)d_in[11];
  float* out = (float*)d_out;

  float* ws = (float*)d_ws;
  const size_t SZ_CP = (size_t)Bc * Cc * Pc;
  const size_t SZ_IP = (size_t)Bc * INNERc * Pc;
  const size_t SZ_L  = (size_t)Bc * HEADSc * Fc * Pc;
  const size_t SZ_SV = (size_t)Bc * HEADSc * Fc * DHc;   // 32768
  float* ehs_ln = ws;
  float* Qt = ehs_ln + SZ_CP;
  float* Kt = Qt + SZ_IP;
  float* Vt = Kt + SZ_IP;
  float* L1 = Vt + SZ_IP;
  float* Lc = L1 + SZ_L;
  float* sv = Lc + SZ_L;
  float* svp = sv + SZ_SV;                               // [18][32768]
  float* OA = svp + (size_t)CHUNKS * SZ_SV;

  ln_kernel<<<dim3((Bc * Pc) / 64), dim3(256), 0, stream>>>(ehs, gamma, beta, ehs_ln);
  gemm_at_kernel<<<dim3(Pc / 64, INNERc / 64, Bc), dim3(256), 0, stream>>>(hs, Wq, Qt, Cc, INNERc);
  gemm_at_kernel<<<dim3(Pc / 64, INNERc / 64, Bc), dim3(256), 0, stream>>>(ehs_ln, Wk, Kt, Cc, INNERc);
  gemm_at_kernel<<<dim3(Pc / 64, INNERc / 64, Bc), dim3(256), 0, stream>>>(ehs_ln, Wv, Vt, Cc, INNERc);
  logits_kernel<<<dim3(Pc / 256, HEADSc, Bc), dim3(256), 0, stream>>>(Kt, exf, scale, L1);
  softmax_rows_kernel<<<dim3(Bc * HEADSc * Fc), dim3(256), 0, stream>>>(L1);
  logits_kernel<<<dim3(Pc / 256, HEADSc, Bc), dim3(256), 0, stream>>>(Qt, dif, scale, Lc);
  softmax_f_kernel<<<dim3(Pc / 256, HEADSc, Bc), dim3(256), 0, stream>>>(Lc);
  sv_part_kernel<<<dim3(CHUNKS, HEADSc, Bc), dim3(256), 0, stream>>>(L1, Vt, svp);
  sv_reduce_kernel<<<dim3((16 * Fc * DHc) / 256), dim3(256), 0, stream>>>(svp, sv);
  oa_kernel<<<dim3(Pc / 64, HEADSc, Bc), dim3(256), 0, stream>>>(Lc, sv, OA);
  final_gemm_kernel<<<dim3(Pc / 64, Cc / 64, Bc), dim3(256), 0, stream>>>(OA, Wo, bo, hs, scale, out);
}

// Round 3
// 205.633 us; speedup vs baseline: 2.3621x; 1.6025x over previous
//
#include <hip/hip_runtime.h>
#include <math.h>

#define Bc 2
#define Cc 320
#define Pc 2304
#define HEADSc 8
#define DHc 64
#define INNERc 512
#define Fc 32
#define LN_EPS 1e-5f
#define CHUNKS 18
#define CHUNK_P (Pc / CHUNKS)  // 128

typedef __attribute__((ext_vector_type(8))) short bf16x8;
typedef __attribute__((ext_vector_type(4))) float f32x4;

static __device__ __forceinline__ ushort f2bf(float x) {
  uint u = __builtin_bit_cast(uint, x);
  u = (u + 0x7fffu + ((u >> 16) & 1u)) >> 16;
  return (ushort)u;
}

// ---------------------------------------------------------------------------
// 1. LayerNorm over channel dim of ehs [B, C, P] -> ehs_ln [B, C, P] fp32
// ---------------------------------------------------------------------------
__global__ __launch_bounds__(256) void ln_kernel(
    const float* __restrict__ ehs, const float* __restrict__ gamma,
    const float* __restrict__ beta, float* __restrict__ out) {
  int lane = threadIdx.x & 63, g = threadIdx.x >> 6;
  int gp = blockIdx.x * 64 + lane;
  int b = gp / Pc, p = gp % Pc;
  const float* base = ehs + (size_t)b * Cc * Pc + p;

  float sum = 0.f, sumsq = 0.f;
  for (int c = g * 80; c < (g + 1) * 80; ++c) {
    float x = base[(size_t)c * Pc];
    sum += x; sumsq += x * x;
  }
  __shared__ float s1[4][64], s2[4][64];
  __shared__ float mrs[64][2];
  s1[g][lane] = sum; s2[g][lane] = sumsq;
  __syncthreads();
  if (threadIdx.x < 64) {
    int l = threadIdx.x;
    float ts = s1[0][l] + s1[1][l] + s1[2][l] + s1[3][l];
    float tq = s2[0][l] + s2[1][l] + s2[2][l] + s2[3][l];
    float mean = ts / (float)Cc;
    float var = tq / (float)Cc - mean * mean;
    mrs[l][0] = mean;
    mrs[l][1] = rsqrtf(var + LN_EPS);
  }
  __syncthreads();
  float mean = mrs[lane][0], rstd = mrs[lane][1];
  float* ob = out + (size_t)b * Cc * Pc + p;
  for (int c = g * 80; c < (g + 1) * 80; ++c) {
    float x = base[(size_t)c * Pc];
    ob[(size_t)c * Pc] = (x - mean) * rstd * gamma[c] + beta[c];
  }
}

// ---------------------------------------------------------------------------
// Transpose+cast tile: src fp32 [R][C] -> dst bf16 [C][R]; 64x64 per block
// ---------------------------------------------------------------------------
static __device__ void transpose_tile(const float* __restrict__ src,
                                      ushort* __restrict__ dst, int R, int C,
                                      int r0, int c0, int tid,
                                      float (*t)[65]) {
#pragma unroll
  for (int it = 0; it < 4; ++it) {
    int lin = it * 256 + tid;           // 1024 float4
    int rr = lin >> 4, c4 = lin & 15;
    float4 v = *(const float4*)(&src[(size_t)(r0 + rr) * C + c0 + c4 * 4]);
    t[rr][c4 * 4 + 0] = v.x; t[rr][c4 * 4 + 1] = v.y;
    t[rr][c4 * 4 + 2] = v.z; t[rr][c4 * 4 + 3] = v.w;
  }
  __syncthreads();
#pragma unroll
  for (int it = 0; it < 2; ++it) {
    int lin = it * 256 + tid;           // 512 chunks of 8
    int cc = lin >> 3, r8 = lin & 7;
    ushort tmp[8];
#pragma unroll
    for (int j = 0; j < 8; ++j) tmp[j] = f2bf(t[r8 * 8 + j][cc]);
    *(uint4*)(&dst[(size_t)(c0 + cc) * R + r0 + r8 * 8]) = *(const uint4*)tmp;
  }
}

// z: 0-1 -> hs batch b, 2-3 -> ehs_ln batch b. grid (36, 5, 4)
__global__ __launch_bounds__(256) void transpose_act_kernel(
    const float* __restrict__ hs, const float* __restrict__ ehs_ln,
    ushort* __restrict__ hsT, ushort* __restrict__ ehsT) {
  __shared__ float t[64][65];
  int z = blockIdx.z, b = z & 1, which = z >> 1;
  const float* src = (which ? ehs_ln : hs) + (size_t)b * Cc * Pc;
  ushort* dst = (which ? ehsT : hsT) + (size_t)b * Pc * Cc;
  transpose_tile(src, dst, Cc, Pc, blockIdx.y * 64, blockIdx.x * 64,
                 threadIdx.x, t);
}

__global__ __launch_bounds__(256) void transpose_w_kernel(
    const float* __restrict__ src, ushort* __restrict__ dst, int R, int C) {
  __shared__ float t[64][65];
  transpose_tile(src, dst, R, C, blockIdx.y * 64, blockIdx.x * 64,
                 threadIdx.x, t);
}

// ---------------------------------------------------------------------------
// Fused filter-weight product: G[h*32+f][c] = sum_d filt[f][h*64+d]*W[c][h*64+d]
// grid (8 heads, 2: y=0 -> (exf,Wk)->Gk, y=1 -> (dif,Wq)->Gq)
// ---------------------------------------------------------------------------
__global__ __launch_bounds__(256) void gfuse_kernel(
    const float* __restrict__ exf, const float* __restrict__ Wk,
    const float* __restrict__ dif, const float* __restrict__ Wq,
    ushort* __restrict__ Gk, ushort* __restrict__ Gq) {
  int h = blockIdx.x;
  const float* filt = blockIdx.y ? dif : exf;
  const float* W = blockIdx.y ? Wq : Wk;
  ushort* G = blockIdx.y ? Gq : Gk;
  __shared__ float ef[Fc][66];
  __shared__ float wk[64][65];
  int tid = threadIdx.x;
  for (int l = tid; l < Fc * DHc; l += 256) {
    int f = l >> 6, d = l & 63;
    ef[f][d] = filt[(size_t)f * INNERc + h * 64 + d];
  }
  int f = tid >> 3, slot = tid & 7;
  for (int c0 = 0; c0 < Cc; c0 += 64) {
    __syncthreads();
    for (int l = tid; l < 4096; l += 256) {
      int cc = l >> 6, d = l & 63;
      wk[cc][d] = W[(size_t)(c0 + cc) * INNERc + h * 64 + d];
    }
    __syncthreads();
#pragma unroll
    for (int j = 0; j < 8; ++j) {
      int cc = slot * 8 + j;
      float a = 0.f;
#pragma unroll
      for (int d = 0; d < 64; ++d) a += ef[f][d] * wk[cc][d];
      G[(size_t)(h * Fc + f) * Cc + c0 + cc] = f2bf(a);
    }
  }
}

// ---------------------------------------------------------------------------
// MFMA GEMM: Out[b][m][pos] = sum_k A[m][k] * Bt[b][pos][k]  (both bf16)
// Block tile 64(M) x 128(N), 4 waves each 64x32. BK=64. XOR chunk swizzle.
// Optional epilogue: + bias[m] + scale * res[b][m][pos]
// ---------------------------------------------------------------------------
__global__ __launch_bounds__(256) void gemm_mfma_kernel(
    const ushort* __restrict__ A, const ushort* __restrict__ Bt,
    float* __restrict__ Out, int K, int Mdim,
    const float* __restrict__ bias, const float* __restrict__ res,
    const float* __restrict__ scale_p) {
  int b = blockIdx.z;
  int n0 = blockIdx.x * 128, m0 = blockIdx.y * 64;
  int tid = threadIdx.x, lane = tid & 63, wv = tid >> 6;
  int l15 = lane & 15, kq = lane >> 4;
  __shared__ alignas(16) ushort As[64 * 64];
  __shared__ alignas(16) ushort Bs[128 * 64];
  const ushort* Ab = A + (size_t)m0 * K;
  const ushort* Bb = Bt + ((size_t)b * Pc + n0) * K;

  f32x4 acc[4][2] = {};

  for (int k0 = 0; k0 < K; k0 += 64) {
#pragma unroll
    for (int it = 0; it < 2; ++it) {
      int lin = it * 256 + tid;         // 512 chunks: 64 rows x 8
      int row = lin >> 3, p = lin & 7;
      int lc = p ^ (row & 7);
      *(uint4*)(&As[row * 64 + p * 8]) =
          *(const uint4*)(Ab + (size_t)row * K + k0 + lc * 8);
    }
#pragma unroll
    for (int it = 0; it < 4; ++it) {
      int lin = it * 256 + tid;         // 1024 chunks: 128 rows x 8
      int row = lin >> 3, p = lin & 7;
      int lc = p ^ (row & 7);
      *(uint4*)(&Bs[row * 64 + p * 8]) =
          *(const uint4*)(Bb + (size_t)row * K + k0 + lc * 8);
    }
    __syncthreads();
#pragma unroll
    for (int s = 0; s < 2; ++s) {
      bf16x8 af[4], bfr[2];
#pragma unroll
      for (int mt = 0; mt < 4; ++mt) {
        int m = mt * 16 + l15;
        int p = (s * 4 + kq) ^ (m & 7);
        af[mt] = *(const bf16x8*)(&As[m * 64 + p * 8]);
      }
#pragma unroll
      for (int nt = 0; nt < 2; ++nt) {
        int n = wv * 32 + nt * 16 + l15;
        int p = (s * 4 + kq) ^ (n & 7);
        bfr[nt] = *(const bf16x8*)(&Bs[n * 64 + p * 8]);
      }
#pragma unroll
      for (int mt = 0; mt < 4; ++mt)
#pragma unroll
        for (int nt = 0; nt < 2; ++nt)
          acc[mt][nt] = __builtin_amdgcn_mfma_f32_16x16x32_bf16(
              af[mt], bfr[nt], acc[mt][nt], 0, 0, 0);
    }
    __syncthreads();
  }

  float* Ob = Out + ((size_t)b * Mdim + m0) * Pc + n0;
  if (bias != nullptr) {
    float s = scale_p[0];
    const float* rb = res + ((size_t)b * Mdim + m0) * Pc + n0;
#pragma unroll
    for (int mt = 0; mt < 4; ++mt)
#pragma unroll
      for (int nt = 0; nt < 2; ++nt) {
        int ncol = wv * 32 + nt * 16 + l15;
#pragma unroll
        for (int r = 0; r < 4; ++r) {
          int m = mt * 16 + kq * 4 + r;
          Ob[(size_t)m * Pc + ncol] =
              acc[mt][nt][r] + bias[m0 + m] + s * rb[(size_t)m * Pc + ncol];
        }
      }
  } else {
#pragma unroll
    for (int mt = 0; mt < 4; ++mt)
#pragma unroll
      for (int nt = 0; nt < 2; ++nt) {
        int ncol = wv * 32 + nt * 16 + l15;
#pragma unroll
        for (int r = 0; r < 4; ++r) {
          int m = mt * 16 + kq * 4 + r;
          Ob[(size_t)m * Pc + ncol] = acc[mt][nt][r];
        }
      }
  }
}

// ---------------------------------------------------------------------------
// Softmax along pos (row length P), logits scaled by s before softmax
// ---------------------------------------------------------------------------
__global__ __launch_bounds__(256) void softmax_rows_kernel(
    float* __restrict__ L, const float* __restrict__ scale_p) {
  __shared__ float red[4];
  float s = scale_p[0];
  float* Lr = L + (size_t)blockIdx.x * Pc;
  int tid = threadIdx.x, lane = tid & 63, wv = tid >> 6;
  float vals[9];
  float m = -1e30f;
#pragma unroll
  for (int i = 0; i < 9; ++i) {
    vals[i] = Lr[tid + 256 * i] * s;
    m = fmaxf(m, vals[i]);
  }
#pragma unroll
  for (int o = 32; o > 0; o >>= 1) m = fmaxf(m, __shfl_xor(m, o));
  if (lane == 0) red[wv] = m;
  __syncthreads();
  m = fmaxf(fmaxf(red[0], red[1]), fmaxf(red[2], red[3]));
  __syncthreads();
  float sum = 0.f;
#pragma unroll
  for (int i = 0; i < 9; ++i) {
    vals[i] = __expf(vals[i] - m);
    sum += vals[i];
  }
#pragma unroll
  for (int o = 32; o > 0; o >>= 1) sum += __shfl_xor(sum, o);
  if (lane == 0) red[wv] = sum;
  __syncthreads();
  sum = red[0] + red[1] + red[2] + red[3];
  float inv = 1.f / sum;
#pragma unroll
  for (int i = 0; i < 9; ++i) Lr[tid + 256 * i] = vals[i] * inv;
}

// ---------------------------------------------------------------------------
// Softmax along f (32), logits scaled by s
// ---------------------------------------------------------------------------
__global__ __launch_bounds__(256) void softmax_f_kernel(
    float* __restrict__ L, const float* __restrict__ scale_p) {
  int b = blockIdx.z, h = blockIdx.y;
  float s = scale_p[0];
  int pos = blockIdx.x * 256 + threadIdx.x;
  float* Lb = L + ((size_t)(b * HEADSc + h) * Fc) * Pc + pos;
  float v[Fc];
  float m = -1e30f;
#pragma unroll
  for (int f = 0; f < Fc; ++f) {
    v[f] = Lb[(size_t)f * Pc] * s;
    m = fmaxf(m, v[f]);
  }
  float sum = 0.f;
#pragma unroll
  for (int f = 0; f < Fc; ++f) {
    v[f] = __expf(v[f] - m);
    sum += v[f];
  }
  float inv = 1.f / sum;
#pragma unroll
  for (int f = 0; f < Fc; ++f) Lb[(size_t)f * Pc] = v[f] * inv;
}

// ---------------------------------------------------------------------------
// sv partials: split-K over 18 chunks of 128. svp [chunk][bh][f][d]
// ---------------------------------------------------------------------------
__global__ __launch_bounds__(256) void sv_part_kernel(
    const float* __restrict__ spatial, const float* __restrict__ Vt,
    float* __restrict__ svp) {
  int b = blockIdx.z, h = blockIdx.y, c = blockIdx.x;
  int tid = threadIdx.x;
  int tx = tid & 15, ty = tid >> 4;
  int p0base = c * CHUNK_P;
  const float* sp = spatial + ((size_t)(b * HEADSc + h)) * Fc * Pc;
  const float* vb = Vt + ((size_t)b * INNERc + h * DHc) * Pc;

  __shared__ float sp_s[64][34];
  __shared__ float v_s[64][68];

  float acc[2][4] = {};
  for (int t = 0; t < CHUNK_P; t += 64) {
    int p0 = p0base + t;
    for (int l = tid; l < Fc * 64; l += 256) {
      int f = l >> 6, pp = l & 63;
      sp_s[pp][f] = sp[(size_t)f * Pc + p0 + pp];
    }
    for (int l = tid; l < DHc * 64; l += 256) {
      int d = l >> 6, pp = l & 63;
      v_s[pp][d] = vb[(size_t)d * Pc + p0 + pp];
    }
    __syncthreads();
#pragma unroll
    for (int kk = 0; kk < 64; ++kk) {
      float2 a = *reinterpret_cast<const float2*>(&sp_s[kk][ty * 2]);
      float4 bv = *reinterpret_cast<const float4*>(&v_s[kk][tx * 4]);
      acc[0][0] += a.x * bv.x; acc[0][1] += a.x * bv.y;
      acc[0][2] += a.x * bv.z; acc[0][3] += a.x * bv.w;
      acc[1][0] += a.y * bv.x; acc[1][1] += a.y * bv.y;
      acc[1][2] += a.y * bv.z; acc[1][3] += a.y * bv.w;
    }
    __syncthreads();
  }
  int bh = b * HEADSc + h;
  float* op = svp + ((size_t)c * 16 + bh) * (Fc * DHc);
#pragma unroll
  for (int i = 0; i < 2; ++i) {
    int f = ty * 2 + i;
    *reinterpret_cast<float4*>(&op[(size_t)f * DHc + tx * 4]) =
        make_float4(acc[i][0], acc[i][1], acc[i][2], acc[i][3]);
  }
}

__global__ __launch_bounds__(256) void sv_reduce_kernel(
    const float* __restrict__ svp, float* __restrict__ sv) {
  int idx = blockIdx.x * 256 + threadIdx.x;
  float s = 0.f;
#pragma unroll
  for (int c = 0; c < CHUNKS; ++c) s += svp[(size_t)c * 32768 + idx];
  sv[idx] = s;
}

// ---------------------------------------------------------------------------
// OAT[b][pos][h*64+d] (bf16) = sum_f channel[b][h][f][pos] * sv[b][h][f][d]
// LDS transpose so the global write is along inner (k-contiguous for GEMM).
// ---------------------------------------------------------------------------
__global__ __launch_bounds__(256) void oa_kernel(
    const float* __restrict__ channel, const float* __restrict__ sv,
    ushort* __restrict__ OAT) {
  int b = blockIdx.z, h = blockIdx.y;
  int tid = threadIdx.x;
  int lane = tid & 63, wv = tid >> 6;
  int pos0 = blockIdx.x * 64;
  __shared__ float svl[Fc][DHc];
  __shared__ float tile[64][65];
  for (int l = tid; l < Fc * DHc; l += 256)
    svl[l >> 6][l & 63] = sv[((size_t)(b * HEADSc + h)) * Fc * DHc + l];
  __syncthreads();
  const float* ch = channel + (((size_t)(b * HEADSc + h)) * Fc) * Pc + pos0 + lane;
  float acc[16] = {};
  for (int f = 0; f < Fc; ++f) {
    float cf = ch[(size_t)f * Pc];
#pragma unroll
    for (int dd = 0; dd < 16; ++dd) acc[dd] += cf * svl[f][wv * 16 + dd];
  }
#pragma unroll
  for (int dd = 0; dd < 16; ++dd) tile[lane][wv * 16 + dd] = acc[dd];
  __syncthreads();
#pragma unroll
  for (int it = 0; it < 2; ++it) {
    int lin = it * 256 + tid;
    int p = lin >> 3, c8 = lin & 7;
    ushort tmp[8];
#pragma unroll
    for (int j = 0; j < 8; ++j) tmp[j] = f2bf(tile[p][c8 * 8 + j]);
    *(uint4*)(&OAT[((size_t)b * Pc + pos0 + p) * INNERc + h * DHc + c8 * 8]) =
        *(const uint4*)tmp;
  }
}

// ---------------------------------------------------------------------------
extern "C" void kernel_launch(void* const* d_in, const int* in_sizes, int n_in,
                              void* d_out, int out_size, void* d_ws, size_t ws_size,
                              hipStream_t stream) {
  const float* hs    = (const float*)d_in[0];
  const float* ehs   = (const float*)d_in[1];
  const float* Wq    = (const float*)d_in[2];
  const float* Wk    = (const float*)d_in[3];
  const float* Wv    = (const float*)d_in[4];
  const float* Wo    = (const float*)d_in[5];
  const float* bo    = (const float*)d_in[6];
  const float* gamma = (const float*)d_in[7];
  const float* beta  = (const float*)d_in[8];
  const float* exf   = (const float*)d_in[9];
  const float* dif   = (const float*)d_in[10];
  const float* scale = (const float*)d_in[11];
  float* out = (float*)d_out;

  float* ws = (float*)d_ws;
  float* ehs_ln = ws;                          // 1,474,560 f
  float* Vt  = ehs_ln + 1474560;               // 2,359,296 f
  float* L1  = Vt + 2359296;                   // 1,179,648 f
  float* Lc  = L1 + 1179648;                   // 1,179,648 f
  float* sv  = Lc + 1179648;                   //    32,768 f
  float* svp = sv + 32768;                     //   589,824 f
  ushort* hsT  = (ushort*)(svp + 589824);      // 1,474,560 us
  ushort* ehsT = hsT + 1474560;                // 1,474,560 us
  ushort* WvT  = ehsT + 1474560;               //   163,840 us
  ushort* WoT  = WvT + 163840;                 //   163,840 us
  ushort* Gk   = WoT + 163840;                 //    81,920 us
  ushort* Gq   = Gk + 81920;                   //    81,920 us
  ushort* OAT  = Gq + 81920;                   // 2,359,296 us

  // 1. LayerNorm (fp32)
  ln_kernel<<<dim3((Bc * Pc) / 64), dim3(256), 0, stream>>>(ehs, gamma, beta, ehs_ln);
  // 2. Transposes / casts to bf16 K-contiguous layouts
  transpose_act_kernel<<<dim3(Pc / 64, Cc / 64, 4), dim3(256), 0, stream>>>(
      hs, ehs_ln, hsT, ehsT);
  transpose_w_kernel<<<dim3(INNERc / 64, Cc / 64), dim3(256), 0, stream>>>(
      Wv, WvT, Cc, INNERc);  // [320][512] -> [512][320]
  transpose_w_kernel<<<dim3(Cc / 64, INNERc / 64), dim3(256), 0, stream>>>(
      Wo, WoT, INNERc, Cc);  // [512][320] -> [320][512]
  // 3. Filter-weight fusion: Gk = exf*Wk, Gq = dif*Wq  [256][320] bf16
  gfuse_kernel<<<dim3(HEADSc, 2), dim3(256), 0, stream>>>(exf, Wk, dif, Wq, Gk, Gq);
  // 4. MFMA GEMMs: V projection + both logit sets
  gemm_mfma_kernel<<<dim3(Pc / 128, INNERc / 64, Bc), dim3(256), 0, stream>>>(
      WvT, ehsT, Vt, Cc, INNERc, nullptr, nullptr, nullptr);
  gemm_mfma_kernel<<<dim3(Pc / 128, 256 / 64, Bc), dim3(256), 0, stream>>>(
      Gk, ehsT, L1, Cc, 256, nullptr, nullptr, nullptr);
  gemm_mfma_kernel<<<dim3(Pc / 128, 256 / 64, Bc), dim3(256), 0, stream>>>(
      Gq, hsT, Lc, Cc, 256, nullptr, nullptr, nullptr);
  // 5. Softmaxes (scale folded in)
  softmax_rows_kernel<<<dim3(Bc * HEADSc * Fc), dim3(256), 0, stream>>>(L1, scale);
  softmax_f_kernel<<<dim3(Pc / 256, HEADSc, Bc), dim3(256), 0, stream>>>(Lc, scale);
  // 6. sv = spatial @ V  (split-K) ; reduce
  sv_part_kernel<<<dim3(CHUNKS, HEADSc, Bc), dim3(256), 0, stream>>>(L1, Vt, svp);
  sv_reduce_kernel<<<dim3((16 * Fc * DHc) / 256), dim3(256), 0, stream>>>(svp, sv);
  // 7. OA^T = (channel^T @ sv) in [pos][inner] bf16
  oa_kernel<<<dim3(Pc / 64, HEADSc, Bc), dim3(256), 0, stream>>>(Lc, sv, OAT);
  // 8. Output projection + bias + scaled residual (MFMA, fused epilogue)
  gemm_mfma_kernel<<<dim3(Pc / 128, Cc / 64, Bc), dim3(256), 0, stream>>>(
      WoT, OAT, out, INNERc, Cc, bo, hs, scale);
}

// Round 4
// 179.428 us; speedup vs baseline: 2.7071x; 1.1461x over previous
//
#include <hip/hip_runtime.h>
#include <math.h>

#define Bc 2
#define Cc 320
#define Pc 2304
#define HEADSc 8
#define DHc 64
#define INNERc 512
#define Fc 32
#define LN_EPS 1e-5f
#define CHUNKS 18
#define CHUNK_P (Pc / CHUNKS)  // 128

typedef __attribute__((ext_vector_type(8))) short bf16x8;
typedef __attribute__((ext_vector_type(4))) float f32x4;

static __device__ __forceinline__ ushort f2bf(float x) {
  uint u = __builtin_bit_cast(uint, x);
  u = (u + 0x7fffu + ((u >> 16) & 1u)) >> 16;
  return (ushort)u;
}

// ---------------------------------------------------------------------------
// 1. LayerNorm over channel dim of ehs [B, C, P] -> ehs_ln [B, C, P] fp32
// ---------------------------------------------------------------------------
__global__ __launch_bounds__(256) void ln_kernel(
    const float* __restrict__ ehs, const float* __restrict__ gamma,
    const float* __restrict__ beta, float* __restrict__ out) {
  int lane = threadIdx.x & 63, g = threadIdx.x >> 6;
  int gp = blockIdx.x * 64 + lane;
  int b = gp / Pc, p = gp % Pc;
  const float* base = ehs + (size_t)b * Cc * Pc + p;

  float sum = 0.f, sumsq = 0.f;
  for (int c = g * 80; c < (g + 1) * 80; ++c) {
    float x = base[(size_t)c * Pc];
    sum += x; sumsq += x * x;
  }
  __shared__ float s1[4][64], s2[4][64];
  __shared__ float mrs[64][2];
  s1[g][lane] = sum; s2[g][lane] = sumsq;
  __syncthreads();
  if (threadIdx.x < 64) {
    int l = threadIdx.x;
    float ts = s1[0][l] + s1[1][l] + s1[2][l] + s1[3][l];
    float tq = s2[0][l] + s2[1][l] + s2[2][l] + s2[3][l];
    float mean = ts / (float)Cc;
    float var = tq / (float)Cc - mean * mean;
    mrs[l][0] = mean;
    mrs[l][1] = rsqrtf(var + LN_EPS);
  }
  __syncthreads();
  float mean = mrs[lane][0], rstd = mrs[lane][1];
  float* ob = out + (size_t)b * Cc * Pc + p;
  for (int c = g * 80; c < (g + 1) * 80; ++c) {
    float x = base[(size_t)c * Pc];
    ob[(size_t)c * Pc] = (x - mean) * rstd * gamma[c] + beta[c];
  }
}

// ---------------------------------------------------------------------------
// Transpose+cast tile: src fp32 [R][C] -> dst bf16 [C][R]; 64x64 per block
// ---------------------------------------------------------------------------
static __device__ void transpose_tile(const float* __restrict__ src,
                                      ushort* __restrict__ dst, int R, int C,
                                      int r0, int c0, int tid,
                                      float (*t)[65]) {
#pragma unroll
  for (int it = 0; it < 4; ++it) {
    int lin = it * 256 + tid;           // 1024 float4
    int rr = lin >> 4, c4 = lin & 15;
    float4 v = *(const float4*)(&src[(size_t)(r0 + rr) * C + c0 + c4 * 4]);
    t[rr][c4 * 4 + 0] = v.x; t[rr][c4 * 4 + 1] = v.y;
    t[rr][c4 * 4 + 2] = v.z; t[rr][c4 * 4 + 3] = v.w;
  }
  __syncthreads();
#pragma unroll
  for (int it = 0; it < 2; ++it) {
    int lin = it * 256 + tid;           // 512 chunks of 8
    int cc = lin >> 3, r8 = lin & 7;
    ushort tmp[8];
#pragma unroll
    for (int j = 0; j < 8; ++j) tmp[j] = f2bf(t[r8 * 8 + j][cc]);
    *(uint4*)(&dst[(size_t)(c0 + cc) * R + r0 + r8 * 8]) = *(const uint4*)tmp;
  }
}

// z: 0-1 -> hs batch b, 2-3 -> ehs_ln batch b. grid (36, 5, 4)
__global__ __launch_bounds__(256) void transpose_act_kernel(
    const float* __restrict__ hs, const float* __restrict__ ehs_ln,
    ushort* __restrict__ hsT, ushort* __restrict__ ehsT) {
  __shared__ float t[64][65];
  int z = blockIdx.z, b = z & 1, which = z >> 1;
  const float* src = (which ? ehs_ln : hs) + (size_t)b * Cc * Pc;
  ushort* dst = (which ? ehsT : hsT) + (size_t)b * Pc * Cc;
  transpose_tile(src, dst, Cc, Pc, blockIdx.y * 64, blockIdx.x * 64,
                 threadIdx.x, t);
}

__global__ __launch_bounds__(256) void transpose_w_kernel(
    const float* __restrict__ src, ushort* __restrict__ dst, int R, int C) {
  __shared__ float t[64][65];
  transpose_tile(src, dst, R, C, blockIdx.y * 64, blockIdx.x * 64,
                 threadIdx.x, t);
}

// ---------------------------------------------------------------------------
// Fused filter-weight product: G[h*32+f][c] = sum_d filt[f][h*64+d]*W[c][h*64+d]
// grid (Cc/64, HEADS, 2): z=0 -> (exf,Wk)->Gk, z=1 -> (dif,Wq)->Gq.
// One 32(f) x 64(c) output tile per block; K=64 fully in LDS; 8 lanes share
// each ef/wk row (same-address broadcast), so LDS reads are conflict-free.
// ---------------------------------------------------------------------------
__global__ __launch_bounds__(256) void gfuse_kernel(
    const float* __restrict__ exf, const float* __restrict__ Wk,
    const float* __restrict__ dif, const float* __restrict__ Wq,
    ushort* __restrict__ Gk, ushort* __restrict__ Gq) {
  int c0 = blockIdx.x * 64, h = blockIdx.y;
  const float* filt = blockIdx.z ? dif : exf;
  const float* W = blockIdx.z ? Wq : Wk;
  ushort* G = blockIdx.z ? Gq : Gk;
  __shared__ float ef[Fc][66];
  __shared__ float wk[64][65];
  int tid = threadIdx.x;
  for (int l = tid; l < Fc * DHc; l += 256) {     // 2048, coalesced in d
    int f = l >> 6, d = l & 63;
    ef[f][d] = filt[(size_t)f * INNERc + h * 64 + d];
  }
  for (int l = tid; l < 64 * DHc; l += 256) {     // 4096, coalesced in d
    int cc = l >> 6, d = l & 63;
    wk[cc][d] = W[(size_t)(c0 + cc) * INNERc + h * 64 + d];
  }
  __syncthreads();
  int f = tid >> 3, cbase = tid & 7;
  float acc[8] = {};
#pragma unroll
  for (int d4 = 0; d4 < DHc; d4 += 4) {
    float4 a = *(const float4*)(&ef[f][d4]);
#pragma unroll
    for (int j = 0; j < 8; ++j) {
      float4 b = *(const float4*)(&wk[cbase + j * 8][d4]);
      acc[j] += a.x * b.x + a.y * b.y + a.z * b.z + a.w * b.w;
    }
  }
#pragma unroll
  for (int j = 0; j < 8; ++j)
    G[(size_t)(h * Fc + f) * Cc + c0 + cbase + j * 8] = f2bf(acc[j]);
}

// ---------------------------------------------------------------------------
// MFMA GEMM: Out[b][m][pos] = sum_k A[m][k] * Bt[b][pos][k]  (both bf16)
// Block tile 64(M) x 128(N), 4 waves each 64x32. BK=64. XOR chunk swizzle.
// Optional epilogue: + bias[m] + scale * res[b][m][pos]
// ---------------------------------------------------------------------------
__global__ __launch_bounds__(256) void gemm_mfma_kernel(
    const ushort* __restrict__ A, const ushort* __restrict__ Bt,
    float* __restrict__ Out, int K, int Mdim,
    const float* __restrict__ bias, const float* __restrict__ res,
    const float* __restrict__ scale_p) {
  int b = blockIdx.z;
  int n0 = blockIdx.x * 128, m0 = blockIdx.y * 64;
  int tid = threadIdx.x, lane = tid & 63, wv = tid >> 6;
  int l15 = lane & 15, kq = lane >> 4;
  __shared__ alignas(16) ushort As[64 * 64];
  __shared__ alignas(16) ushort Bs[128 * 64];
  const ushort* Ab = A + (size_t)m0 * K;
  const ushort* Bb = Bt + ((size_t)b * Pc + n0) * K;

  f32x4 acc[4][2] = {};

  for (int k0 = 0; k0 < K; k0 += 64) {
#pragma unroll
    for (int it = 0; it < 2; ++it) {
      int lin = it * 256 + tid;         // 512 chunks: 64 rows x 8
      int row = lin >> 3, p = lin & 7;
      int lc = p ^ (row & 7);
      *(uint4*)(&As[row * 64 + p * 8]) =
          *(const uint4*)(Ab + (size_t)row * K + k0 + lc * 8);
    }
#pragma unroll
    for (int it = 0; it < 4; ++it) {
      int lin = it * 256 + tid;         // 1024 chunks: 128 rows x 8
      int row = lin >> 3, p = lin & 7;
      int lc = p ^ (row & 7);
      *(uint4*)(&Bs[row * 64 + p * 8]) =
          *(const uint4*)(Bb + (size_t)row * K + k0 + lc * 8);
    }
    __syncthreads();
#pragma unroll
    for (int s = 0; s < 2; ++s) {
      bf16x8 af[4], bfr[2];
#pragma unroll
      for (int mt = 0; mt < 4; ++mt) {
        int m = mt * 16 + l15;
        int p = (s * 4 + kq) ^ (m & 7);
        af[mt] = *(const bf16x8*)(&As[m * 64 + p * 8]);
      }
#pragma unroll
      for (int nt = 0; nt < 2; ++nt) {
        int n = wv * 32 + nt * 16 + l15;
        int p = (s * 4 + kq) ^ (n & 7);
        bfr[nt] = *(const bf16x8*)(&Bs[n * 64 + p * 8]);
      }
#pragma unroll
      for (int mt = 0; mt < 4; ++mt)
#pragma unroll
        for (int nt = 0; nt < 2; ++nt)
          acc[mt][nt] = __builtin_amdgcn_mfma_f32_16x16x32_bf16(
              af[mt], bfr[nt], acc[mt][nt], 0, 0, 0);
    }
    __syncthreads();
  }

  float* Ob = Out + ((size_t)b * Mdim + m0) * Pc + n0;
  if (bias != nullptr) {
    float s = scale_p[0];
    const float* rb = res + ((size_t)b * Mdim + m0) * Pc + n0;
#pragma unroll
    for (int mt = 0; mt < 4; ++mt)
#pragma unroll
      for (int nt = 0; nt < 2; ++nt) {
        int ncol = wv * 32 + nt * 16 + l15;
#pragma unroll
        for (int r = 0; r < 4; ++r) {
          int m = mt * 16 + kq * 4 + r;
          Ob[(size_t)m * Pc + ncol] =
              acc[mt][nt][r] + bias[m0 + m] + s * rb[(size_t)m * Pc + ncol];
        }
      }
  } else {
#pragma unroll
    for (int mt = 0; mt < 4; ++mt)
#pragma unroll
      for (int nt = 0; nt < 2; ++nt) {
        int ncol = wv * 32 + nt * 16 + l15;
#pragma unroll
        for (int r = 0; r < 4; ++r) {
          int m = mt * 16 + kq * 4 + r;
          Ob[(size_t)m * Pc + ncol] = acc[mt][nt][r];
        }
      }
  }
}

// ---------------------------------------------------------------------------
// Softmax along pos (row length P), logits scaled by s before softmax
// ---------------------------------------------------------------------------
__global__ __launch_bounds__(256) void softmax_rows_kernel(
    float* __restrict__ L, const float* __restrict__ scale_p) {
  __shared__ float red[4];
  float s = scale_p[0];
  float* Lr = L + (size_t)blockIdx.x * Pc;
  int tid = threadIdx.x, lane = tid & 63, wv = tid >> 6;
  float vals[9];
  float m = -1e30f;
#pragma unroll
  for (int i = 0; i < 9; ++i) {
    vals[i] = Lr[tid + 256 * i] * s;
    m = fmaxf(m, vals[i]);
  }
#pragma unroll
  for (int o = 32; o > 0; o >>= 1) m = fmaxf(m, __shfl_xor(m, o));
  if (lane == 0) red[wv] = m;
  __syncthreads();
  m = fmaxf(fmaxf(red[0], red[1]), fmaxf(red[2], red[3]));
  __syncthreads();
  float sum = 0.f;
#pragma unroll
  for (int i = 0; i < 9; ++i) {
    vals[i] = __expf(vals[i] - m);
    sum += vals[i];
  }
#pragma unroll
  for (int o = 32; o > 0; o >>= 1) sum += __shfl_xor(sum, o);
  if (lane == 0) red[wv] = sum;
  __syncthreads();
  sum = red[0] + red[1] + red[2] + red[3];
  float inv = 1.f / sum;
#pragma unroll
  for (int i = 0; i < 9; ++i) Lr[tid + 256 * i] = vals[i] * inv;
}

// ---------------------------------------------------------------------------
// Softmax along f (32), logits scaled by s
// ---------------------------------------------------------------------------
__global__ __launch_bounds__(256) void softmax_f_kernel(
    float* __restrict__ L, const float* __restrict__ scale_p) {
  int b = blockIdx.z, h = blockIdx.y;
  float s = scale_p[0];
  int pos = blockIdx.x * 256 + threadIdx.x;
  float* Lb = L + ((size_t)(b * HEADSc + h) * Fc) * Pc + pos;
  float v[Fc];
  float m = -1e30f;
#pragma unroll
  for (int f = 0; f < Fc; ++f) {
    v[f] = Lb[(size_t)f * Pc] * s;
    m = fmaxf(m, v[f]);
  }
  float sum = 0.f;
#pragma unroll
  for (int f = 0; f < Fc; ++f) {
    v[f] = __expf(v[f] - m);
    sum += v[f];
  }
  float inv = 1.f / sum;
#pragma unroll
  for (int f = 0; f < Fc; ++f) Lb[(size_t)f * Pc] = v[f] * inv;
}

// ---------------------------------------------------------------------------
// sv partials: split-K over 18 chunks of 128. svp [chunk][bh][f][d]
// ---------------------------------------------------------------------------
__global__ __launch_bounds__(256) void sv_part_kernel(
    const float* __restrict__ spatial, const float* __restrict__ Vt,
    float* __restrict__ svp) {
  int b = blockIdx.z, h = blockIdx.y, c = blockIdx.x;
  int tid = threadIdx.x;
  int tx = tid & 15, ty = tid >> 4;
  int p0base = c * CHUNK_P;
  const float* sp = spatial + ((size_t)(b * HEADSc + h)) * Fc * Pc;
  const float* vb = Vt + ((size_t)b * INNERc + h * DHc) * Pc;

  __shared__ float sp_s[64][34];
  __shared__ float v_s[64][68];

  float acc[2][4] = {};
  for (int t = 0; t < CHUNK_P; t += 64) {
    int p0 = p0base + t;
    for (int l = tid; l < Fc * 64; l += 256) {
      int f = l >> 6, pp = l & 63;
      sp_s[pp][f] = sp[(size_t)f * Pc + p0 + pp];
    }
    for (int l = tid; l < DHc * 64; l += 256) {
      int d = l >> 6, pp = l & 63;
      v_s[pp][d] = vb[(size_t)d * Pc + p0 + pp];
    }
    __syncthreads();
#pragma unroll
    for (int kk = 0; kk < 64; ++kk) {
      float2 a = *reinterpret_cast<const float2*>(&sp_s[kk][ty * 2]);
      float4 bv = *reinterpret_cast<const float4*>(&v_s[kk][tx * 4]);
      acc[0][0] += a.x * bv.x; acc[0][1] += a.x * bv.y;
      acc[0][2] += a.x * bv.z; acc[0][3] += a.x * bv.w;
      acc[1][0] += a.y * bv.x; acc[1][1] += a.y * bv.y;
      acc[1][2] += a.y * bv.z; acc[1][3] += a.y * bv.w;
    }
    __syncthreads();
  }
  int bh = b * HEADSc + h;
  float* op = svp + ((size_t)c * 16 + bh) * (Fc * DHc);
#pragma unroll
  for (int i = 0; i < 2; ++i) {
    int f = ty * 2 + i;
    *reinterpret_cast<float4*>(&op[(size_t)f * DHc + tx * 4]) =
        make_float4(acc[i][0], acc[i][1], acc[i][2], acc[i][3]);
  }
}

__global__ __launch_bounds__(256) void sv_reduce_kernel(
    const float* __restrict__ svp, float* __restrict__ sv) {
  int idx = blockIdx.x * 256 + threadIdx.x;
  float s = 0.f;
#pragma unroll
  for (int c = 0; c < CHUNKS; ++c) s += svp[(size_t)c * 32768 + idx];
  sv[idx] = s;
}

// ---------------------------------------------------------------------------
// OAT[b][pos][h*64+d] (bf16) = sum_f channel[b][h][f][pos] * sv[b][h][f][d]
// ---------------------------------------------------------------------------
__global__ __launch_bounds__(256) void oa_kernel(
    const float* __restrict__ channel, const float* __restrict__ sv,
    ushort* __restrict__ OAT) {
  int b = blockIdx.z, h = blockIdx.y;
  int tid = threadIdx.x;
  int lane = tid & 63, wv = tid >> 6;
  int pos0 = blockIdx.x * 64;
  __shared__ float svl[Fc][DHc];
  __shared__ float tile[64][65];
  for (int l = tid; l < Fc * DHc; l += 256)
    svl[l >> 6][l & 63] = sv[((size_t)(b * HEADSc + h)) * Fc * DHc + l];
  __syncthreads();
  const float* ch = channel + (((size_t)(b * HEADSc + h)) * Fc) * Pc + pos0 + lane;
  float acc[16] = {};
  for (int f = 0; f < Fc; ++f) {
    float cf = ch[(size_t)f * Pc];
#pragma unroll
    for (int dd = 0; dd < 16; ++dd) acc[dd] += cf * svl[f][wv * 16 + dd];
  }
#pragma unroll
  for (int dd = 0; dd < 16; ++dd) tile[lane][wv * 16 + dd] = acc[dd];
  __syncthreads();
#pragma unroll
  for (int it = 0; it < 2; ++it) {
    int lin = it * 256 + tid;
    int p = lin >> 3, c8 = lin & 7;
    ushort tmp[8];
#pragma unroll
    for (int j = 0; j < 8; ++j) tmp[j] = f2bf(tile[p][c8 * 8 + j]);
    *(uint4*)(&OAT[((size_t)b * Pc + pos0 + p) * INNERc + h * DHc + c8 * 8]) =
        *(const uint4*)tmp;
  }
}

// ---------------------------------------------------------------------------
extern "C" void kernel_launch(void* const* d_in, const int* in_sizes, int n_in,
                              void* d_out, int out_size, void* d_ws, size_t ws_size,
                              hipStream_t stream) {
  const float* hs    = (const float*)d_in[0];
  const float* ehs   = (const float*)d_in[1];
  const float* Wq    = (const float*)d_in[2];
  const float* Wk    = (const float*)d_in[3];
  const float* Wv    = (const float*)d_in[4];
  const float* Wo    = (const float*)d_in[5];
  const float* bo    = (const float*)d_in[6];
  const float* gamma = (const float*)d_in[7];
  const float* beta  = (const float*)d_in[8];
  const float* exf   = (const float*)d_in[9];
  const float* dif   = (const float*)d_in[10];
  const float* scale = (const float*)d_in[11];
  float* out = (float*)d_out;

  float* ws = (float*)d_ws;
  float* ehs_ln = ws;                          // 1,474,560 f
  float* Vt  = ehs_ln + 1474560;               // 2,359,296 f
  float* L1  = Vt + 2359296;                   // 1,179,648 f
  float* Lc  = L1 + 1179648;                   // 1,179,648 f
  float* sv  = Lc + 1179648;                   //    32,768 f
  float* svp = sv + 32768;                     //   589,824 f
  ushort* hsT  = (ushort*)(svp + 589824);      // 1,474,560 us
  ushort* ehsT = hsT + 1474560;                // 1,474,560 us
  ushort* WvT  = ehsT + 1474560;               //   163,840 us
  ushort* WoT  = WvT + 163840;                 //   163,840 us
  ushort* Gk   = WoT + 163840;                 //    81,920 us
  ushort* Gq   = Gk + 81920;                   //    81,920 us
  ushort* OAT  = Gq + 81920;                   // 2,359,296 us

  // 1. LayerNorm (fp32)
  ln_kernel<<<dim3((Bc * Pc) / 64), dim3(256), 0, stream>>>(ehs, gamma, beta, ehs_ln);
  // 2. Transposes / casts to bf16 K-contiguous layouts
  transpose_act_kernel<<<dim3(Pc / 64, Cc / 64, 4), dim3(256), 0, stream>>>(
      hs, ehs_ln, hsT, ehsT);
  transpose_w_kernel<<<dim3(INNERc / 64, Cc / 64), dim3(256), 0, stream>>>(
      Wv, WvT, Cc, INNERc);  // [320][512] -> [512][320]
  transpose_w_kernel<<<dim3(Cc / 64, INNERc / 64), dim3(256), 0, stream>>>(
      Wo, WoT, INNERc, Cc);  // [512][320] -> [320][512]
  // 3. Filter-weight fusion: Gk = exf*Wk, Gq = dif*Wq  [256][320] bf16
  gfuse_kernel<<<dim3(Cc / 64, HEADSc, 2), dim3(256), 0, stream>>>(
      exf, Wk, dif, Wq, Gk, Gq);
  // 4. MFMA GEMMs: V projection + both logit sets
  gemm_mfma_kernel<<<dim3(Pc / 128, INNERc / 64, Bc), dim3(256), 0, stream>>>(
      WvT, ehsT, Vt, Cc, INNERc, nullptr, nullptr, nullptr);
  gemm_mfma_kernel<<<dim3(Pc / 128, 256 / 64, Bc), dim3(256), 0, stream>>>(
      Gk, ehsT, L1, Cc, 256, nullptr, nullptr, nullptr);
  gemm_mfma_kernel<<<dim3(Pc / 128, 256 / 64, Bc), dim3(256), 0, stream>>>(
      Gq, hsT, Lc, Cc, 256, nullptr, nullptr, nullptr);
  // 5. Softmaxes (scale folded in)
  softmax_rows_kernel<<<dim3(Bc * HEADSc * Fc), dim3(256), 0, stream>>>(L1, scale);
  softmax_f_kernel<<<dim3(Pc / 256, HEADSc, Bc), dim3(256), 0, stream>>>(Lc, scale);
  // 6. sv = spatial @ V  (split-K) ; reduce
  sv_part_kernel<<<dim3(CHUNKS, HEADSc, Bc), dim3(256), 0, stream>>>(L1, Vt, svp);
  sv_reduce_kernel<<<dim3((16 * Fc * DHc) / 256), dim3(256), 0, stream>>>(svp, sv);
  // 7. OA^T = (channel^T @ sv) in [pos][inner] bf16
  oa_kernel<<<dim3(Pc / 64, HEADSc, Bc), dim3(256), 0, stream>>>(Lc, sv, OAT);
  // 8. Output projection + bias + scaled residual (MFMA, fused epilogue)
  gemm_mfma_kernel<<<dim3(Pc / 128, Cc / 64, Bc), dim3(256), 0, stream>>>(
      WoT, OAT, out, INNERc, Cc, bo, hs, scale);
}

// Round 5
// 157.332 us; speedup vs baseline: 3.0873x; 1.1404x over previous
//
#include <hip/hip_runtime.h>
#include <math.h>

#define Bc 2
#define Cc 320
#define Pc 2304
#define HEADSc 8
#define DHc 64
#define INNERc 512
#define Fc 32
#define LN_EPS 1e-5f
#define CHUNKS 18
#define CHUNK_P (Pc / CHUNKS)  // 128

typedef __attribute__((ext_vector_type(8))) short bf16x8;
typedef __attribute__((ext_vector_type(4))) float f32x4;

static __device__ __forceinline__ ushort f2bf(float x) {
  uint u = __builtin_bit_cast(uint, x);
  u = (u + 0x7fffu + ((u >> 16) & 1u)) >> 16;
  return (ushort)u;
}
static __device__ __forceinline__ float bf2f(ushort u) {
  return __builtin_bit_cast(float, ((uint)u) << 16);
}

// ---------------------------------------------------------------------------
// 1. LN stats per (b,pos): mean + rstd over C=320.  grid 72 x 256.
// ---------------------------------------------------------------------------
__global__ __launch_bounds__(256) void stats_kernel(
    const float* __restrict__ ehs, float* __restrict__ mu,
    float* __restrict__ rstd) {
  int lane = threadIdx.x & 63, g = threadIdx.x >> 6;
  int gp = blockIdx.x * 64 + lane;
  int b = gp / Pc, p = gp % Pc;
  const float* base = ehs + (size_t)b * Cc * Pc + p;
  float sum = 0.f, sumsq = 0.f;
  for (int c = g * 80; c < (g + 1) * 80; ++c) {
    float x = base[(size_t)c * Pc];
    sum += x; sumsq += x * x;
  }
  __shared__ float s1[4][64], s2[4][64];
  s1[g][lane] = sum; s2[g][lane] = sumsq;
  __syncthreads();
  if (threadIdx.x < 64) {
    int l = threadIdx.x;
    float ts = s1[0][l] + s1[1][l] + s1[2][l] + s1[3][l];
    float tq = s2[0][l] + s2[1][l] + s2[2][l] + s2[3][l];
    float mean = ts / (float)Cc;
    float var = tq / (float)Cc - mean * mean;
    int gp2 = blockIdx.x * 64 + l;
    mu[gp2] = mean;
    rstd[gp2] = rsqrtf(var + LN_EPS);
  }
}

// ---------------------------------------------------------------------------
// Transpose+cast tile helper: src fp32 [R][C] -> dst bf16 [C][R]
// ---------------------------------------------------------------------------
static __device__ void transpose_tile(const float* __restrict__ src,
                                      ushort* __restrict__ dst, int R, int C,
                                      int r0, int c0, int tid,
                                      float (*t)[65]) {
#pragma unroll
  for (int it = 0; it < 4; ++it) {
    int lin = it * 256 + tid;
    int rr = lin >> 4, c4 = lin & 15;
    float4 v = *(const float4*)(&src[(size_t)(r0 + rr) * C + c0 + c4 * 4]);
    t[rr][c4 * 4 + 0] = v.x; t[rr][c4 * 4 + 1] = v.y;
    t[rr][c4 * 4 + 2] = v.z; t[rr][c4 * 4 + 3] = v.w;
  }
  __syncthreads();
#pragma unroll
  for (int it = 0; it < 2; ++it) {
    int lin = it * 256 + tid;
    int cc = lin >> 3, r8 = lin & 7;
    ushort tmp[8];
#pragma unroll
    for (int j = 0; j < 8; ++j) tmp[j] = f2bf(t[r8 * 8 + j][cc]);
    *(uint4*)(&dst[(size_t)(c0 + cc) * R + r0 + r8 * 8]) = *(const uint4*)tmp;
  }
}

// ---------------------------------------------------------------------------
// 2. Activation transpose to [pos][C] bf16; LN applied inline for ehs path.
//    grid (36, 5, 4): z = b + 2*which (which: 0->hs, 1->ehs)
// ---------------------------------------------------------------------------
__global__ __launch_bounds__(256) void transpose_act_kernel(
    const float* __restrict__ hs, const float* __restrict__ ehs,
    const float* __restrict__ mu, const float* __restrict__ rstd,
    const float* __restrict__ gamma, const float* __restrict__ beta,
    ushort* __restrict__ hsT, ushort* __restrict__ ehsT) {
  __shared__ float t[64][65];
  __shared__ float lmu[64], lrs[64], lgam[64], lbet[64];
  int z = blockIdx.z, b = z & 1, which = z >> 1;
  int r0 = blockIdx.y * 64, c0 = blockIdx.x * 64;  // r0: channel, c0: pos
  int tid = threadIdx.x;
  const float* src = (which ? ehs : hs) + (size_t)b * Cc * Pc;
  ushort* dst = (which ? ehsT : hsT) + (size_t)b * Pc * Cc;
  if (which && tid < 64) {
    lmu[tid] = mu[b * Pc + c0 + tid];
    lrs[tid] = rstd[b * Pc + c0 + tid];
    lgam[tid] = gamma[r0 + tid];
    lbet[tid] = beta[r0 + tid];
  }
#pragma unroll
  for (int it = 0; it < 4; ++it) {
    int lin = it * 256 + tid;
    int rr = lin >> 4, c4 = lin & 15;
    float4 v = *(const float4*)(&src[(size_t)(r0 + rr) * Pc + c0 + c4 * 4]);
    t[rr][c4 * 4 + 0] = v.x; t[rr][c4 * 4 + 1] = v.y;
    t[rr][c4 * 4 + 2] = v.z; t[rr][c4 * 4 + 3] = v.w;
  }
  __syncthreads();
#pragma unroll
  for (int it = 0; it < 2; ++it) {
    int lin = it * 256 + tid;
    int cc = lin >> 3, r8 = lin & 7;
    ushort tmp[8];
    float m_ = which ? lmu[cc] : 0.f, rs_ = which ? lrs[cc] : 1.f;
#pragma unroll
    for (int j = 0; j < 8; ++j) {
      int ch = r8 * 8 + j;
      float x = t[ch][cc];
      float val = which ? (x - m_) * rs_ * lgam[ch] + lbet[ch] : x;
      tmp[j] = f2bf(val);
    }
    *(uint4*)(&dst[(size_t)(c0 + cc) * Cc + r0 + r8 * 8]) = *(const uint4*)tmp;
  }
}

// ---------------------------------------------------------------------------
// 3. Weight prep (one launch, 160 blocks):
//    [0,40)  WvT  [512][320] bf16 from Wv [320][512]
//    [40,80) WoT  [320][512] bf16 from Wo [512][320]
//    [80,160) gfuse: G[h*32+f][c] = sum_d filt[f][h*64+d] * W[c][h*64+d]
// ---------------------------------------------------------------------------
__global__ __launch_bounds__(256) void prep_w_kernel(
    const float* __restrict__ Wv, const float* __restrict__ Wo,
    const float* __restrict__ exf, const float* __restrict__ Wk,
    const float* __restrict__ dif, const float* __restrict__ Wq,
    ushort* __restrict__ WvT, ushort* __restrict__ WoT,
    ushort* __restrict__ Gk, ushort* __restrict__ Gq) {
  __shared__ float smem[32 * 66 + 64 * 65];  // 6272 floats
  int idx = blockIdx.x, tid = threadIdx.x;
  if (idx < 40) {
    float (*t)[65] = (float(*)[65])smem;
    transpose_tile(Wv, WvT, Cc, INNERc, (idx / 8) * 64, (idx % 8) * 64, tid, t);
  } else if (idx < 80) {
    int i = idx - 40;
    float (*t)[65] = (float(*)[65])smem;
    transpose_tile(Wo, WoT, INNERc, Cc, (i / 5) * 64, (i % 5) * 64, tid, t);
  } else {
    int i = idx - 80;
    int c0 = (i % 5) * 64, h = (i / 5) % 8, zz = i / 40;
    const float* filt = zz ? dif : exf;
    const float* W = zz ? Wq : Wk;
    ushort* G = zz ? Gq : Gk;
    float (*ef)[66] = (float(*)[66])smem;
    float (*wk)[65] = (float(*)[65])(smem + 32 * 66);
    for (int l = tid; l < Fc * DHc; l += 256) {
      int f = l >> 6, d = l & 63;
      ef[f][d] = filt[(size_t)f * INNERc + h * 64 + d];
    }
    for (int l = tid; l < 64 * DHc; l += 256) {
      int cc = l >> 6, d = l & 63;
      wk[cc][d] = W[(size_t)(c0 + cc) * INNERc + h * 64 + d];
    }
    __syncthreads();
    int f = tid >> 3, cbase = tid & 7;
    float acc[8] = {};
#pragma unroll
    for (int d4 = 0; d4 < DHc; d4 += 4) {
      float4 a = *(const float4*)(&ef[f][d4]);
#pragma unroll
      for (int j = 0; j < 8; ++j) {
        float4 b = *(const float4*)(&wk[cbase + j * 8][d4]);
        acc[j] += a.x * b.x + a.y * b.y + a.z * b.z + a.w * b.w;
      }
    }
#pragma unroll
    for (int j = 0; j < 8; ++j)
      G[(size_t)(h * Fc + f) * Cc + c0 + cbase + j * 8] = f2bf(acc[j]);
  }
}

// ---------------------------------------------------------------------------
// 4. Combined projection GEMM (K=320 for all three):
//    y in [0,8):   Vt[b][y*64..][pos]  = WvT . ehsT   (bf16 out)
//    y in [8,12):  L1[b][(y-8)*64..]   = Gk  . ehsT   (fp32 logits)
//    y in [12,16): Lc[b][(y-12)*64..]  = Gq  . hsT    (fp32 logits)
//    Block tile 64(M) x 128(N), 4 waves, BK=64, XOR swizzle.
// ---------------------------------------------------------------------------
__global__ __launch_bounds__(256) void gemm_all_kernel(
    const ushort* __restrict__ WvT, const ushort* __restrict__ Gk,
    const ushort* __restrict__ Gq, const ushort* __restrict__ ehsT,
    const ushort* __restrict__ hsT, ushort* __restrict__ Vt,
    float* __restrict__ L1, float* __restrict__ Lc) {
  const int K = Cc;
  int b = blockIdx.z, y = blockIdx.y;
  const ushort* A;
  const ushort* Bt;
  ushort* OutB = nullptr;
  float* OutF = nullptr;
  if (y < 8) {
    int m0 = y * 64;
    A = WvT + (size_t)m0 * K; Bt = ehsT;
    OutB = Vt + ((size_t)b * INNERc + m0) * Pc;
  } else if (y < 12) {
    int m0 = (y - 8) * 64;
    A = Gk + (size_t)m0 * K; Bt = ehsT;
    OutF = L1 + ((size_t)b * 256 + m0) * Pc;
  } else {
    int m0 = (y - 12) * 64;
    A = Gq + (size_t)m0 * K; Bt = hsT;
    OutF = Lc + ((size_t)b * 256 + m0) * Pc;
  }
  int n0 = blockIdx.x * 128;
  int tid = threadIdx.x, lane = tid & 63, wv = tid >> 6;
  int l15 = lane & 15, kq = lane >> 4;
  __shared__ alignas(16) ushort As[64 * 64];
  __shared__ alignas(16) ushort Bs[128 * 64];
  const ushort* Bb = Bt + ((size_t)b * Pc + n0) * K;

  f32x4 acc[4][2] = {};
  for (int k0 = 0; k0 < K; k0 += 64) {
#pragma unroll
    for (int it = 0; it < 2; ++it) {
      int lin = it * 256 + tid;
      int row = lin >> 3, p = lin & 7;
      int lc = p ^ (row & 7);
      *(uint4*)(&As[row * 64 + p * 8]) =
          *(const uint4*)(A + (size_t)row * K + k0 + lc * 8);
    }
#pragma unroll
    for (int it = 0; it < 4; ++it) {
      int lin = it * 256 + tid;
      int row = lin >> 3, p = lin & 7;
      int lc = p ^ (row & 7);
      *(uint4*)(&Bs[row * 64 + p * 8]) =
          *(const uint4*)(Bb + (size_t)row * K + k0 + lc * 8);
    }
    __syncthreads();
#pragma unroll
    for (int s = 0; s < 2; ++s) {
      bf16x8 af[4], bfr[2];
#pragma unroll
      for (int mt = 0; mt < 4; ++mt) {
        int m = mt * 16 + l15;
        int p = (s * 4 + kq) ^ (m & 7);
        af[mt] = *(const bf16x8*)(&As[m * 64 + p * 8]);
      }
#pragma unroll
      for (int nt = 0; nt < 2; ++nt) {
        int n = wv * 32 + nt * 16 + l15;
        int p = (s * 4 + kq) ^ (n & 7);
        bfr[nt] = *(const bf16x8*)(&Bs[n * 64 + p * 8]);
      }
#pragma unroll
      for (int mt = 0; mt < 4; ++mt)
#pragma unroll
        for (int nt = 0; nt < 2; ++nt)
          acc[mt][nt] = __builtin_amdgcn_mfma_f32_16x16x32_bf16(
              af[mt], bfr[nt], acc[mt][nt], 0, 0, 0);
    }
    __syncthreads();
  }
  if (OutB) {
#pragma unroll
    for (int mt = 0; mt < 4; ++mt)
#pragma unroll
      for (int nt = 0; nt < 2; ++nt) {
        int ncol = n0 + wv * 32 + nt * 16 + l15;
#pragma unroll
        for (int r = 0; r < 4; ++r) {
          int m = mt * 16 + kq * 4 + r;
          OutB[(size_t)m * Pc + ncol] = f2bf(acc[mt][nt][r]);
        }
      }
  } else {
#pragma unroll
    for (int mt = 0; mt < 4; ++mt)
#pragma unroll
      for (int nt = 0; nt < 2; ++nt) {
        int ncol = n0 + wv * 32 + nt * 16 + l15;
#pragma unroll
        for (int r = 0; r < 4; ++r) {
          int m = mt * 16 + kq * 4 + r;
          OutF[(size_t)m * Pc + ncol] = acc[mt][nt][r];
        }
      }
  }
}

// ---------------------------------------------------------------------------
// 5. Row stats for spatial softmax: m = max(s*x), inv = 1/sum(exp(s*x-m))
// ---------------------------------------------------------------------------
__global__ __launch_bounds__(256) void rowstat_kernel(
    const float* __restrict__ L, const float* __restrict__ scale_p,
    float* __restrict__ rowm, float* __restrict__ rowinv) {
  __shared__ float red[4];
  float s = scale_p[0];
  const float* Lr = L + (size_t)blockIdx.x * Pc;
  int tid = threadIdx.x, lane = tid & 63, wv = tid >> 6;
  float vals[9];
  float m = -1e30f;
#pragma unroll
  for (int i = 0; i < 9; ++i) {
    vals[i] = Lr[tid + 256 * i] * s;
    m = fmaxf(m, vals[i]);
  }
#pragma unroll
  for (int o = 32; o > 0; o >>= 1) m = fmaxf(m, __shfl_xor(m, o));
  if (lane == 0) red[wv] = m;
  __syncthreads();
  m = fmaxf(fmaxf(red[0], red[1]), fmaxf(red[2], red[3]));
  __syncthreads();
  float sum = 0.f;
#pragma unroll
  for (int i = 0; i < 9; ++i) sum += __expf(vals[i] - m);
#pragma unroll
  for (int o = 32; o > 0; o >>= 1) sum += __shfl_xor(sum, o);
  if (lane == 0) red[wv] = sum;
  __syncthreads();
  if (tid == 0) {
    sum = red[0] + red[1] + red[2] + red[3];
    rowm[blockIdx.x] = m;
    rowinv[blockIdx.x] = 1.f / sum;
  }
}

// ---------------------------------------------------------------------------
// 6. sv partials with inline softmax-apply; V is bf16.
//    svp [chunk][bh][f][d]; grid (18, 8, 2)
// ---------------------------------------------------------------------------
__global__ __launch_bounds__(256) void sv_part_kernel(
    const float* __restrict__ L1, const ushort* __restrict__ Vt,
    const float* __restrict__ rowm, const float* __restrict__ rowinv,
    const float* __restrict__ scale_p, float* __restrict__ svp) {
  int b = blockIdx.z, h = blockIdx.y, c = blockIdx.x;
  int tid = threadIdx.x;
  int tx = tid & 15, ty = tid >> 4;
  int p0base = c * CHUNK_P;
  const float* sp = L1 + ((size_t)(b * HEADSc + h)) * Fc * Pc;
  const ushort* vb = Vt + ((size_t)b * INNERc + h * DHc) * Pc;

  __shared__ float sp_s[64][34];
  __shared__ float v_s[64][68];
  __shared__ float lm[Fc], li[Fc];
  if (tid < Fc) {
    int row0 = (b * HEADSc + h) * Fc;
    lm[tid] = rowm[row0 + tid];
    li[tid] = rowinv[row0 + tid];
  }
  __syncthreads();
  float s = scale_p[0];

  float acc[2][4] = {};
  for (int t = 0; t < CHUNK_P; t += 64) {
    int p0 = p0base + t;
    for (int l = tid; l < Fc * 64; l += 256) {
      int f = l >> 6, pp = l & 63;
      float raw = sp[(size_t)f * Pc + p0 + pp];
      sp_s[pp][f] = __expf(s * raw - lm[f]) * li[f];
    }
    for (int l = tid; l < DHc * 64; l += 256) {
      int d = l >> 6, pp = l & 63;
      v_s[pp][d] = bf2f(vb[(size_t)d * Pc + p0 + pp]);
    }
    __syncthreads();
#pragma unroll
    for (int kk = 0; kk < 64; ++kk) {
      float2 a = *reinterpret_cast<const float2*>(&sp_s[kk][ty * 2]);
      float4 bv = *reinterpret_cast<const float4*>(&v_s[kk][tx * 4]);
      acc[0][0] += a.x * bv.x; acc[0][1] += a.x * bv.y;
      acc[0][2] += a.x * bv.z; acc[0][3] += a.x * bv.w;
      acc[1][0] += a.y * bv.x; acc[1][1] += a.y * bv.y;
      acc[1][2] += a.y * bv.z; acc[1][3] += a.y * bv.w;
    }
    __syncthreads();
  }
  int bh = b * HEADSc + h;
  float* op = svp + ((size_t)c * 16 + bh) * (Fc * DHc);
#pragma unroll
  for (int i = 0; i < 2; ++i) {
    int f = ty * 2 + i;
    *reinterpret_cast<float4*>(&op[(size_t)f * DHc + tx * 4]) =
        make_float4(acc[i][0], acc[i][1], acc[i][2], acc[i][3]);
  }
}

__global__ __launch_bounds__(256) void sv_reduce_kernel(
    const float* __restrict__ svp, float* __restrict__ sv) {
  int idx = blockIdx.x * 256 + threadIdx.x;
  float s = 0.f;
#pragma unroll
  for (int c = 0; c < CHUNKS; ++c) s += svp[(size_t)c * 32768 + idx];
  sv[idx] = s;
}

// ---------------------------------------------------------------------------
// 7. OAT[b][pos][h*64+d] (bf16) with inline softmax over f of Lc logits.
// ---------------------------------------------------------------------------
__global__ __launch_bounds__(256) void oa_kernel(
    const float* __restrict__ Lc, const float* __restrict__ sv,
    const float* __restrict__ scale_p, ushort* __restrict__ OAT) {
  int b = blockIdx.z, h = blockIdx.y;
  int tid = threadIdx.x;
  int lane = tid & 63, wv = tid >> 6;
  int pos0 = blockIdx.x * 64;
  float s = scale_p[0];
  __shared__ float svl[Fc][DHc];
  __shared__ float tile[64][65];
  for (int l = tid; l < Fc * DHc; l += 256)
    svl[l >> 6][l & 63] = sv[((size_t)(b * HEADSc + h)) * Fc * DHc + l];
  __syncthreads();
  const float* ch = Lc + (((size_t)(b * HEADSc + h)) * Fc) * Pc + pos0 + lane;
  float v[Fc];
  float m = -1e30f;
#pragma unroll
  for (int f = 0; f < Fc; ++f) {
    v[f] = ch[(size_t)f * Pc] * s;
    m = fmaxf(m, v[f]);
  }
  float sum = 0.f;
#pragma unroll
  for (int f = 0; f < Fc; ++f) {
    v[f] = __expf(v[f] - m);
    sum += v[f];
  }
  float inv = 1.f / sum;
  float acc[16] = {};
#pragma unroll
  for (int f = 0; f < Fc; ++f) {
    float cf = v[f] * inv;
#pragma unroll
    for (int dd = 0; dd < 16; ++dd) acc[dd] += cf * svl[f][wv * 16 + dd];
  }
#pragma unroll
  for (int dd = 0; dd < 16; ++dd) tile[lane][wv * 16 + dd] = acc[dd];
  __syncthreads();
#pragma unroll
  for (int it = 0; it < 2; ++it) {
    int lin = it * 256 + tid;
    int p = lin >> 3, c8 = lin & 7;
    ushort tmp[8];
#pragma unroll
    for (int j = 0; j < 8; ++j) tmp[j] = f2bf(tile[p][c8 * 8 + j]);
    *(uint4*)(&OAT[((size_t)b * Pc + pos0 + p) * INNERc + h * DHc + c8 * 8]) =
        *(const uint4*)tmp;
  }
}

// ---------------------------------------------------------------------------
// 8. Final GEMM: out = WoT . OAT + bias + s*res. K=512.
// ---------------------------------------------------------------------------
__global__ __launch_bounds__(256) void gemm_mfma_kernel(
    const ushort* __restrict__ A, const ushort* __restrict__ Bt,
    float* __restrict__ Out, int K, int Mdim,
    const float* __restrict__ bias, const float* __restrict__ res,
    const float* __restrict__ scale_p) {
  int b = blockIdx.z;
  int n0 = blockIdx.x * 128, m0 = blockIdx.y * 64;
  int tid = threadIdx.x, lane = tid & 63, wv = tid >> 6;
  int l15 = lane & 15, kq = lane >> 4;
  __shared__ alignas(16) ushort As[64 * 64];
  __shared__ alignas(16) ushort Bs[128 * 64];
  const ushort* Ab = A + (size_t)m0 * K;
  const ushort* Bb = Bt + ((size_t)b * Pc + n0) * K;

  f32x4 acc[4][2] = {};
  for (int k0 = 0; k0 < K; k0 += 64) {
#pragma unroll
    for (int it = 0; it < 2; ++it) {
      int lin = it * 256 + tid;
      int row = lin >> 3, p = lin & 7;
      int lc = p ^ (row & 7);
      *(uint4*)(&As[row * 64 + p * 8]) =
          *(const uint4*)(Ab + (size_t)row * K + k0 + lc * 8);
    }
#pragma unroll
    for (int it = 0; it < 4; ++it) {
      int lin = it * 256 + tid;
      int row = lin >> 3, p = lin & 7;
      int lc = p ^ (row & 7);
      *(uint4*)(&Bs[row * 64 + p * 8]) =
          *(const uint4*)(Bb + (size_t)row * K + k0 + lc * 8);
    }
    __syncthreads();
#pragma unroll
    for (int s = 0; s < 2; ++s) {
      bf16x8 af[4], bfr[2];
#pragma unroll
      for (int mt = 0; mt < 4; ++mt) {
        int m = mt * 16 + l15;
        int p = (s * 4 + kq) ^ (m & 7);
        af[mt] = *(const bf16x8*)(&As[m * 64 + p * 8]);
      }
#pragma unroll
      for (int nt = 0; nt < 2; ++nt) {
        int n = wv * 32 + nt * 16 + l15;
        int p = (s * 4 + kq) ^ (n & 7);
        bfr[nt] = *(const bf16x8*)(&Bs[n * 64 + p * 8]);
      }
#pragma unroll
      for (int mt = 0; mt < 4; ++mt)
#pragma unroll
        for (int nt = 0; nt < 2; ++nt)
          acc[mt][nt] = __builtin_amdgcn_mfma_f32_16x16x32_bf16(
              af[mt], bfr[nt], acc[mt][nt], 0, 0, 0);
    }
    __syncthreads();
  }
  float s = scale_p[0];
  float* Ob = Out + ((size_t)b * Mdim + m0) * Pc + n0;
  const float* rb = res + ((size_t)b * Mdim + m0) * Pc + n0;
#pragma unroll
  for (int mt = 0; mt < 4; ++mt)
#pragma unroll
    for (int nt = 0; nt < 2; ++nt) {
      int ncol = wv * 32 + nt * 16 + l15;
#pragma unroll
      for (int r = 0; r < 4; ++r) {
        int m = mt * 16 + kq * 4 + r;
        Ob[(size_t)m * Pc + ncol] =
            acc[mt][nt][r] + bias[m0 + m] + s * rb[(size_t)m * Pc + ncol];
      }
    }
}

// ---------------------------------------------------------------------------
extern "C" void kernel_launch(void* const* d_in, const int* in_sizes, int n_in,
                              void* d_out, int out_size, void* d_ws, size_t ws_size,
                              hipStream_t stream) {
  const float* hs    = (const float*)d_in[0];
  const float* ehs   = (const float*)d_in[1];
  const float* Wq    = (const float*)d_in[2];
  const float* Wk    = (const float*)d_in[3];
  const float* Wv    = (const float*)d_in[4];
  const float* Wo    = (const float*)d_in[5];
  const float* bo    = (const float*)d_in[6];
  const float* gamma = (const float*)d_in[7];
  const float* beta  = (const float*)d_in[8];
  const float* exf   = (const float*)d_in[9];
  const float* dif   = (const float*)d_in[10];
  const float* scale = (const float*)d_in[11];
  float* out = (float*)d_out;

  float* ws = (float*)d_ws;
  float* L1   = ws;                       // 1,179,648 f
  float* Lc   = L1 + 1179648;             // 1,179,648 f
  float* sv   = Lc + 1179648;             //    32,768 f
  float* svp  = sv + 32768;               //   589,824 f
  float* mu   = svp + 589824;             //     4,608 f
  float* rstd = mu + 4608;                //     4,608 f
  float* rowm = rstd + 4608;              //       512 f
  float* rowinv = rowm + 512;             //       512 f
  ushort* hsT  = (ushort*)(rowinv + 512); // 1,474,560 us
  ushort* ehsT = hsT + 1474560;           // 1,474,560 us
  ushort* WvT  = ehsT + 1474560;          //   163,840 us
  ushort* WoT  = WvT + 163840;            //   163,840 us
  ushort* Gk   = WoT + 163840;            //    81,920 us
  ushort* Gq   = Gk + 81920;              //    81,920 us
  ushort* Vt   = Gq + 81920;              // 2,359,296 us
  ushort* OAT  = Vt + 2359296;            // 2,359,296 us

  stats_kernel<<<dim3((Bc * Pc) / 64), dim3(256), 0, stream>>>(ehs, mu, rstd);
  transpose_act_kernel<<<dim3(Pc / 64, Cc / 64, 4), dim3(256), 0, stream>>>(
      hs, ehs, mu, rstd, gamma, beta, hsT, ehsT);
  prep_w_kernel<<<dim3(160), dim3(256), 0, stream>>>(
      Wv, Wo, exf, Wk, dif, Wq, WvT, WoT, Gk, Gq);
  gemm_all_kernel<<<dim3(Pc / 128, 16, Bc), dim3(256), 0, stream>>>(
      WvT, Gk, Gq, ehsT, hsT, Vt, L1, Lc);
  rowstat_kernel<<<dim3(Bc * HEADSc * Fc), dim3(256), 0, stream>>>(
      L1, scale, rowm, rowinv);
  sv_part_kernel<<<dim3(CHUNKS, HEADSc, Bc), dim3(256), 0, stream>>>(
      L1, Vt, rowm, rowinv, scale, svp);
  sv_reduce_kernel<<<dim3((16 * Fc * DHc) / 256), dim3(256), 0, stream>>>(svp, sv);
  oa_kernel<<<dim3(Pc / 64, HEADSc, Bc), dim3(256), 0, stream>>>(
      Lc, sv, scale, OAT);
  gemm_mfma_kernel<<<dim3(Pc / 128, Cc / 64, Bc), dim3(256), 0, stream>>>(
      WoT, OAT, out, INNERc, Cc, bo, hs, scale);
}

// Round 6
// 155.872 us; speedup vs baseline: 3.1162x; 1.0094x over previous
//
#include <hip/hip_runtime.h>
#include <math.h>

#define Bc 2
#define Cc 320
#define Pc 2304
#define HEADSc 8
#define DHc 64
#define INNERc 512
#define Fc 32
#define LN_EPS 1e-5f
#define CHUNKS 18
#define CHUNK_P 128

typedef __attribute__((ext_vector_type(8))) short bf16x8;
typedef __attribute__((ext_vector_type(4))) float f32x4;

static __device__ __forceinline__ ushort f2bf(float x) {
  uint u = __builtin_bit_cast(uint, x);
  u = (u + 0x7fffu + ((u >> 16) & 1u)) >> 16;
  return (ushort)u;
}

// ---------------------------------------------------------------------------
// 1. LN stats per (b,pos): mean + rstd over C=320.
// ---------------------------------------------------------------------------
__global__ __launch_bounds__(256) void stats_kernel(
    const float* __restrict__ ehs, float* __restrict__ mu,
    float* __restrict__ rstd) {
  int lane = threadIdx.x & 63, g = threadIdx.x >> 6;
  int gp = blockIdx.x * 64 + lane;
  int b = gp / Pc, p = gp % Pc;
  const float* base = ehs + (size_t)b * Cc * Pc + p;
  float sum = 0.f, sumsq = 0.f;
  for (int c = g * 80; c < (g + 1) * 80; ++c) {
    float x = base[(size_t)c * Pc];
    sum += x; sumsq += x * x;
  }
  __shared__ float s1[4][64], s2[4][64];
  s1[g][lane] = sum; s2[g][lane] = sumsq;
  __syncthreads();
  if (threadIdx.x < 64) {
    int l = threadIdx.x;
    float ts = s1[0][l] + s1[1][l] + s1[2][l] + s1[3][l];
    float tq = s2[0][l] + s2[1][l] + s2[2][l] + s2[3][l];
    float mean = ts / (float)Cc;
    float var = tq / (float)Cc - mean * mean;
    int gp2 = blockIdx.x * 64 + l;
    mu[gp2] = mean;
    rstd[gp2] = rsqrtf(var + LN_EPS);
  }
}

// ---------------------------------------------------------------------------
// Transpose+cast tile helper: src fp32 [R][C] -> dst bf16 [C][R]
// ---------------------------------------------------------------------------
static __device__ void transpose_tile(const float* __restrict__ src,
                                      ushort* __restrict__ dst, int R, int C,
                                      int r0, int c0, int tid,
                                      float (*t)[65]) {
#pragma unroll
  for (int it = 0; it < 4; ++it) {
    int lin = it * 256 + tid;
    int rr = lin >> 4, c4 = lin & 15;
    float4 v = *(const float4*)(&src[(size_t)(r0 + rr) * C + c0 + c4 * 4]);
    t[rr][c4 * 4 + 0] = v.x; t[rr][c4 * 4 + 1] = v.y;
    t[rr][c4 * 4 + 2] = v.z; t[rr][c4 * 4 + 3] = v.w;
  }
  __syncthreads();
#pragma unroll
  for (int it = 0; it < 2; ++it) {
    int lin = it * 256 + tid;
    int cc = lin >> 3, r8 = lin & 7;
    ushort tmp[8];
#pragma unroll
    for (int j = 0; j < 8; ++j) tmp[j] = f2bf(t[r8 * 8 + j][cc]);
    *(uint4*)(&dst[(size_t)(c0 + cc) * R + r0 + r8 * 8]) = *(const uint4*)tmp;
  }
}

// ---------------------------------------------------------------------------
// 2. Activation transpose to [pos][C] bf16; LN applied inline for ehs path.
// ---------------------------------------------------------------------------
__global__ __launch_bounds__(256) void transpose_act_kernel(
    const float* __restrict__ hs, const float* __restrict__ ehs,
    const float* __restrict__ mu, const float* __restrict__ rstd,
    const float* __restrict__ gamma, const float* __restrict__ beta,
    ushort* __restrict__ hsT, ushort* __restrict__ ehsT) {
  __shared__ float t[64][65];
  __shared__ float lmu[64], lrs[64], lgam[64], lbet[64];
  int z = blockIdx.z, b = z & 1, which = z >> 1;
  int r0 = blockIdx.y * 64, c0 = blockIdx.x * 64;
  int tid = threadIdx.x;
  const float* src = (which ? ehs : hs) + (size_t)b * Cc * Pc;
  ushort* dst = (which ? ehsT : hsT) + (size_t)b * Pc * Cc;
  if (which && tid < 64) {
    lmu[tid] = mu[b * Pc + c0 + tid];
    lrs[tid] = rstd[b * Pc + c0 + tid];
    lgam[tid] = gamma[r0 + tid];
    lbet[tid] = beta[r0 + tid];
  }
#pragma unroll
  for (int it = 0; it < 4; ++it) {
    int lin = it * 256 + tid;
    int rr = lin >> 4, c4 = lin & 15;
    float4 v = *(const float4*)(&src[(size_t)(r0 + rr) * Pc + c0 + c4 * 4]);
    t[rr][c4 * 4 + 0] = v.x; t[rr][c4 * 4 + 1] = v.y;
    t[rr][c4 * 4 + 2] = v.z; t[rr][c4 * 4 + 3] = v.w;
  }
  __syncthreads();
#pragma unroll
  for (int it = 0; it < 2; ++it) {
    int lin = it * 256 + tid;
    int cc = lin >> 3, r8 = lin & 7;
    ushort tmp[8];
    float m_ = which ? lmu[cc] : 0.f, rs_ = which ? lrs[cc] : 1.f;
#pragma unroll
    for (int j = 0; j < 8; ++j) {
      int ch = r8 * 8 + j;
      float x = t[ch][cc];
      float val = which ? (x - m_) * rs_ * lgam[ch] + lbet[ch] : x;
      tmp[j] = f2bf(val);
    }
    *(uint4*)(&dst[(size_t)(c0 + cc) * Cc + r0 + r8 * 8]) = *(const uint4*)tmp;
  }
}

// ---------------------------------------------------------------------------
// 3. Weight prep: WvT, WoT transposes + filter-weight fusion Gk/Gq.
// ---------------------------------------------------------------------------
__global__ __launch_bounds__(256) void prep_w_kernel(
    const float* __restrict__ Wv, const float* __restrict__ Wo,
    const float* __restrict__ exf, const float* __restrict__ Wk,
    const float* __restrict__ dif, const float* __restrict__ Wq,
    ushort* __restrict__ WvT, ushort* __restrict__ WoT,
    ushort* __restrict__ Gk, ushort* __restrict__ Gq) {
  __shared__ float smem[32 * 66 + 64 * 65];
  int idx = blockIdx.x, tid = threadIdx.x;
  if (idx < 40) {
    float (*t)[65] = (float(*)[65])smem;
    transpose_tile(Wv, WvT, Cc, INNERc, (idx / 8) * 64, (idx % 8) * 64, tid, t);
  } else if (idx < 80) {
    int i = idx - 40;
    float (*t)[65] = (float(*)[65])smem;
    transpose_tile(Wo, WoT, INNERc, Cc, (i / 5) * 64, (i % 5) * 64, tid, t);
  } else {
    int i = idx - 80;
    int c0 = (i % 5) * 64, h = (i / 5) % 8, zz = i / 40;
    const float* filt = zz ? dif : exf;
    const float* W = zz ? Wq : Wk;
    ushort* G = zz ? Gq : Gk;
    float (*ef)[66] = (float(*)[66])smem;
    float (*wk)[65] = (float(*)[65])(smem + 32 * 66);
    for (int l = tid; l < Fc * DHc; l += 256) {
      int f = l >> 6, d = l & 63;
      ef[f][d] = filt[(size_t)f * INNERc + h * 64 + d];
    }
    for (int l = tid; l < 64 * DHc; l += 256) {
      int cc = l >> 6, d = l & 63;
      wk[cc][d] = W[(size_t)(c0 + cc) * INNERc + h * 64 + d];
    }
    __syncthreads();
    int f = tid >> 3, cbase = tid & 7;
    float acc[8] = {};
#pragma unroll
    for (int d4 = 0; d4 < DHc; d4 += 4) {
      float4 a = *(const float4*)(&ef[f][d4]);
#pragma unroll
      for (int j = 0; j < 8; ++j) {
        float4 b = *(const float4*)(&wk[cbase + j * 8][d4]);
        acc[j] += a.x * b.x + a.y * b.y + a.z * b.z + a.w * b.w;
      }
    }
#pragma unroll
    for (int j = 0; j < 8; ++j)
      G[(size_t)(h * Fc + f) * Cc + c0 + cbase + j * 8] = f2bf(acc[j]);
  }
}

// ---------------------------------------------------------------------------
// 4. V projection GEMM: Vt[b][m][pos] = sum_k WvT[m][k] * ehsT[b][pos][k]
//    bf16 out. 64x128 tile, grid (18, 8, 2).
// ---------------------------------------------------------------------------
__global__ __launch_bounds__(256) void gemm_v_kernel(
    const ushort* __restrict__ WvT, const ushort* __restrict__ ehsT,
    ushort* __restrict__ Vt) {
  const int K = Cc;
  int b = blockIdx.z, m0 = blockIdx.y * 64, n0 = blockIdx.x * 128;
  int tid = threadIdx.x, lane = tid & 63, wv = tid >> 6;
  int l15 = lane & 15, kq = lane >> 4;
  __shared__ alignas(16) ushort As[64 * 64];
  __shared__ alignas(16) ushort Bs[128 * 64];
  const ushort* Ab = WvT + (size_t)m0 * K;
  const ushort* Bb = ehsT + ((size_t)b * Pc + n0) * K;

  f32x4 acc[4][2] = {};
  for (int k0 = 0; k0 < K; k0 += 64) {
#pragma unroll
    for (int it = 0; it < 2; ++it) {
      int lin = it * 256 + tid;
      int row = lin >> 3, p = lin & 7;
      int lc = p ^ (row & 7);
      *(uint4*)(&As[row * 64 + p * 8]) =
          *(const uint4*)(Ab + (size_t)row * K + k0 + lc * 8);
    }
#pragma unroll
    for (int it = 0; it < 4; ++it) {
      int lin = it * 256 + tid;
      int row = lin >> 3, p = lin & 7;
      int lc = p ^ (row & 7);
      *(uint4*)(&Bs[row * 64 + p * 8]) =
          *(const uint4*)(Bb + (size_t)row * K + k0 + lc * 8);
    }
    __syncthreads();
#pragma unroll
    for (int ss = 0; ss < 2; ++ss) {
      bf16x8 af[4], bfr[2];
#pragma unroll
      for (int mt = 0; mt < 4; ++mt) {
        int m = mt * 16 + l15;
        int p = (ss * 4 + kq) ^ (m & 7);
        af[mt] = *(const bf16x8*)(&As[m * 64 + p * 8]);
      }
#pragma unroll
      for (int nt = 0; nt < 2; ++nt) {
        int n = wv * 32 + nt * 16 + l15;
        int p = (ss * 4 + kq) ^ (n & 7);
        bfr[nt] = *(const bf16x8*)(&Bs[n * 64 + p * 8]);
      }
#pragma unroll
      for (int mt = 0; mt < 4; ++mt)
#pragma unroll
        for (int nt = 0; nt < 2; ++nt)
          acc[mt][nt] = __builtin_amdgcn_mfma_f32_16x16x32_bf16(
              af[mt], bfr[nt], acc[mt][nt], 0, 0, 0);
    }
    __syncthreads();
  }
  ushort* Ob = Vt + ((size_t)b * INNERc + m0) * Pc + n0;
#pragma unroll
  for (int mt = 0; mt < 4; ++mt)
#pragma unroll
    for (int nt = 0; nt < 2; ++nt) {
      int ncol = wv * 32 + nt * 16 + l15;
#pragma unroll
      for (int r = 0; r < 4; ++r) {
        int m = mt * 16 + kq * 4 + r;
        Ob[(size_t)m * Pc + ncol] = f2bf(acc[mt][nt][r]);
      }
    }
}

// ---------------------------------------------------------------------------
// 5. Fused spatial attention chunk (flash-style split-K over 18 chunks):
//    S = Gk_h(32x320) . ehsT_chunk(128x320)^T  (MFMA)
//    local softmax numerator  P = exp(s*S - m_j)  (bf16)
//    O_j = P(32x128) . V(128x64)                 (MFMA)
//    outputs: svp[c][bh][32][64] fp32, mj/lj [c][bh][32]
// ---------------------------------------------------------------------------
__global__ __launch_bounds__(256) void spatial_kernel(
    const ushort* __restrict__ Gk, const ushort* __restrict__ ehsT,
    const ushort* __restrict__ Vt, const float* __restrict__ scale_p,
    float* __restrict__ svp, float* __restrict__ mj, float* __restrict__ lj) {
  int c = blockIdx.x, h = blockIdx.y, b = blockIdx.z;
  int tid = threadIdx.x, lane = tid & 63, wv = tid >> 6;
  int l15 = lane & 15, kq = lane >> 4;
  int pos0 = c * CHUNK_P;
  int bh = b * HEADSc + h;
  float s = scale_p[0];

  __shared__ alignas(16) ushort As[32 * 64];    // Gk k-tile (XOR swizzle)
  __shared__ alignas(16) ushort Bs[128 * 64];   // ehsT k-tile (XOR swizzle)
  __shared__ float Sq[32 * 132];                // scores fp32, pitch 132
  __shared__ alignas(16) ushort P[32 * 136];    // exp numerator bf16, pitch 136
  __shared__ alignas(16) ushort Vs[64 * 136];   // V chunk [d][pos], pitch 136

  // ---- phase 1: S = Gk . ehsT^T (M=32, N=128, K=320)
  const ushort* Ab = Gk + (size_t)(h * Fc) * Cc;
  const ushort* Bb = ehsT + ((size_t)b * Pc + pos0) * Cc;
  f32x4 acc[2][2] = {};
  for (int k0 = 0; k0 < Cc; k0 += 64) {
    {
      int row = tid >> 3, p = tid & 7;
      int lc = p ^ (row & 7);
      *(uint4*)(&As[row * 64 + p * 8]) =
          *(const uint4*)(Ab + (size_t)row * Cc + k0 + lc * 8);
    }
#pragma unroll
    for (int it = 0; it < 4; ++it) {
      int lin = it * 256 + tid;
      int row = lin >> 3, p = lin & 7;
      int lc = p ^ (row & 7);
      *(uint4*)(&Bs[row * 64 + p * 8]) =
          *(const uint4*)(Bb + (size_t)row * Cc + k0 + lc * 8);
    }
    __syncthreads();
#pragma unroll
    for (int ss = 0; ss < 2; ++ss) {
      bf16x8 af[2], bfr[2];
#pragma unroll
      for (int mt = 0; mt < 2; ++mt) {
        int m = mt * 16 + l15;
        int p = (ss * 4 + kq) ^ (m & 7);
        af[mt] = *(const bf16x8*)(&As[m * 64 + p * 8]);
      }
#pragma unroll
      for (int nt = 0; nt < 2; ++nt) {
        int n = wv * 32 + nt * 16 + l15;
        int p = (ss * 4 + kq) ^ (n & 7);
        bfr[nt] = *(const bf16x8*)(&Bs[n * 64 + p * 8]);
      }
#pragma unroll
      for (int mt = 0; mt < 2; ++mt)
#pragma unroll
        for (int nt = 0; nt < 2; ++nt)
          acc[mt][nt] = __builtin_amdgcn_mfma_f32_16x16x32_bf16(
              af[mt], bfr[nt], acc[mt][nt], 0, 0, 0);
    }
    __syncthreads();
  }
#pragma unroll
  for (int mt = 0; mt < 2; ++mt)
#pragma unroll
    for (int nt = 0; nt < 2; ++nt)
#pragma unroll
      for (int r = 0; r < 4; ++r)
        Sq[(mt * 16 + kq * 4 + r) * 132 + wv * 32 + nt * 16 + l15] =
            acc[mt][nt][r];

  // issue V-chunk loads (region independent of Sq/P); overlaps with softmax
  {
    const ushort* vb = Vt + ((size_t)b * INNERc + h * DHc) * Pc + pos0;
#pragma unroll
    for (int it = 0; it < 4; ++it) {
      int lin = it * 256 + tid;
      int row = lin >> 4, p = lin & 15;
      *(uint4*)(&Vs[row * 136 + p * 8]) =
          *(const uint4*)(vb + (size_t)row * Pc + p * 8);
    }
  }
  __syncthreads();

  // ---- phase 2: per-row (f) local max + exp-sum; P = exp(s*S - m)
  {
    int row = tid >> 3, sub = tid & 7;
    float vals[16];
    float m_ = -1e30f;
#pragma unroll
    for (int i = 0; i < 16; ++i) {
      vals[i] = s * Sq[row * 132 + sub * 16 + i];
      m_ = fmaxf(m_, vals[i]);
    }
    m_ = fmaxf(m_, __shfl_xor(m_, 1));
    m_ = fmaxf(m_, __shfl_xor(m_, 2));
    m_ = fmaxf(m_, __shfl_xor(m_, 4));
    float l_ = 0.f;
#pragma unroll
    for (int i = 0; i < 16; i += 2) {
      float e0 = __expf(vals[i] - m_);
      float e1 = __expf(vals[i + 1] - m_);
      l_ += e0 + e1;
      uint pk = (uint)f2bf(e0) | ((uint)f2bf(e1) << 16);
      *(uint*)(&P[row * 136 + sub * 16 + i]) = pk;
    }
    l_ += __shfl_xor(l_, 1);
    l_ += __shfl_xor(l_, 2);
    l_ += __shfl_xor(l_, 4);
    if (sub == 0) {
      mj[((size_t)c * 16 + bh) * Fc + row] = m_;
      lj[((size_t)c * 16 + bh) * Fc + row] = l_;
    }
  }
  __syncthreads();

  // ---- phase 3: O = P(32x128) . V^T  (M=32, N=64, K=128)
  f32x4 acc2[2] = {};
#pragma unroll
  for (int ss = 0; ss < 4; ++ss) {
    bf16x8 af[2];
#pragma unroll
    for (int mt = 0; mt < 2; ++mt)
      af[mt] = *(const bf16x8*)(&P[(mt * 16 + l15) * 136 + ss * 32 + kq * 8]);
    bf16x8 bfr = *(const bf16x8*)(&Vs[(wv * 16 + l15) * 136 + ss * 32 + kq * 8]);
#pragma unroll
    for (int mt = 0; mt < 2; ++mt)
      acc2[mt] = __builtin_amdgcn_mfma_f32_16x16x32_bf16(af[mt], bfr, acc2[mt],
                                                         0, 0, 0);
  }
  float* op = svp + ((size_t)c * 16 + bh) * (Fc * DHc);
#pragma unroll
  for (int mt = 0; mt < 2; ++mt)
#pragma unroll
    for (int r = 0; r < 4; ++r)
      op[(mt * 16 + kq * 4 + r) * DHc + wv * 16 + l15] = acc2[mt][r];
}

// ---------------------------------------------------------------------------
// 6. Online-softmax reduce of 18 chunks -> svT[bh][d][f] bf16 (transposed
//    for the channel kernel's B operand).
// ---------------------------------------------------------------------------
__global__ __launch_bounds__(256) void sv_reduce_kernel(
    const float* __restrict__ svp, const float* __restrict__ mj,
    const float* __restrict__ lj, ushort* __restrict__ svT) {
  int idx = blockIdx.x * 256 + threadIdx.x;  // 32768
  int d = idx & 63, fr = idx >> 6;           // fr = bh*32+f
  int bh = fr >> 5, f = fr & 31;
  float m = -1e30f;
#pragma unroll
  for (int c = 0; c < CHUNKS; ++c)
    m = fmaxf(m, mj[((size_t)c * 16 + bh) * Fc + f]);
  float osum = 0.f, lsum = 0.f;
#pragma unroll
  for (int c = 0; c < CHUNKS; ++c) {
    float w = __expf(mj[((size_t)c * 16 + bh) * Fc + f] - m);
    osum += w * svp[((size_t)c * 16 + bh) * (Fc * DHc) + f * DHc + d];
    lsum += w * lj[((size_t)c * 16 + bh) * Fc + f];
  }
  svT[((size_t)bh * DHc + d) * Fc + f] = f2bf(osum / lsum);
}

// ---------------------------------------------------------------------------
// 7. Fused channel attention: per (64 pos, 2 heads, b):
//    S = Gq_h(32x320) . hsT(64x320)^T (MFMA), softmax over f per pos,
//    O = P^T(64x32) . svT_h(64x32)^T (MFMA) -> OAT[b][pos][h*64+d] bf16
// ---------------------------------------------------------------------------
__global__ __launch_bounds__(256) void channel_kernel(
    const ushort* __restrict__ Gq, const ushort* __restrict__ hsT,
    const ushort* __restrict__ svT, const float* __restrict__ scale_p,
    ushort* __restrict__ OAT) {
  int pb = blockIdx.x, hp = blockIdx.y, b = blockIdx.z;
  int pos0 = pb * 64;
  int tid = threadIdx.x, lane = tid & 63, wv = tid >> 6;
  int l15 = lane & 15, kq = lane >> 4;
  float s = scale_p[0];

  __shared__ alignas(16) ushort Aq[2][32 * 64];  // Gq k-tiles, 2 heads
  __shared__ alignas(16) ushort Bs[64 * 64];     // hsT k-tile
  __shared__ float SO[64 * 68];                  // S (32x64) then O (64x64)
  __shared__ alignas(16) ushort Pt[64 * 40];     // P^T [pos][f] bf16
  __shared__ alignas(16) ushort svs[64 * 40];    // svT_h [d][f] bf16
  __shared__ float red[4 * 64];

  // ---- phase A: S for both heads
  f32x4 acc[2][2] = {};
  const ushort* Bb = hsT + ((size_t)b * Pc + pos0) * Cc;
  for (int k0 = 0; k0 < Cc; k0 += 64) {
#pragma unroll
    for (int it = 0; it < 2; ++it) {
      int lin = it * 256 + tid;
      int hh = lin >> 8, row = (lin >> 3) & 31, p = lin & 7;
      int lc = p ^ (row & 7);
      *(uint4*)(&Aq[hh][row * 64 + p * 8]) = *(const uint4*)(
          Gq + (size_t)((hp * 2 + hh) * Fc + row) * Cc + k0 + lc * 8);
    }
#pragma unroll
    for (int it = 0; it < 2; ++it) {
      int lin = it * 256 + tid;
      int row = lin >> 3, p = lin & 7;
      int lc = p ^ (row & 7);
      *(uint4*)(&Bs[row * 64 + p * 8]) =
          *(const uint4*)(Bb + (size_t)row * Cc + k0 + lc * 8);
    }
    __syncthreads();
#pragma unroll
    for (int ss = 0; ss < 2; ++ss) {
      int n = wv * 16 + l15;
      int pb_ = (ss * 4 + kq) ^ (n & 7);
      bf16x8 bfr = *(const bf16x8*)(&Bs[n * 64 + pb_ * 8]);
#pragma unroll
      for (int hh = 0; hh < 2; ++hh)
#pragma unroll
        for (int mt = 0; mt < 2; ++mt) {
          int m = mt * 16 + l15;
          int pa = (ss * 4 + kq) ^ (m & 7);
          bf16x8 af = *(const bf16x8*)(&Aq[hh][m * 64 + pa * 8]);
          acc[hh][mt] = __builtin_amdgcn_mfma_f32_16x16x32_bf16(
              af, bfr, acc[hh][mt], 0, 0, 0);
        }
    }
    __syncthreads();
  }

  // ---- per-head epilogue
  for (int hh = 0; hh < 2; ++hh) {
    int h = hp * 2 + hh;
    // S -> LDS  (S[f][pos], pitch 68)
#pragma unroll
    for (int mt = 0; mt < 2; ++mt)
#pragma unroll
      for (int r = 0; r < 4; ++r)
        SO[(mt * 16 + kq * 4 + r) * 68 + wv * 16 + l15] = acc[hh][mt][r];
    // svT_h load (independent LDS region, overlaps softmax)
    {
      int rr = tid >> 2, p = tid & 3;
      *(uint4*)(&svs[rr * 40 + p * 8]) = *(const uint4*)(
          svT + ((size_t)(b * HEADSc + h) * DHc + rr) * Fc + p * 8);
    }
    __syncthreads();
    // softmax over f per pos
    {
      int pos = tid & 63, g = tid >> 6;
      float v8[8];
      float pm = -1e30f;
#pragma unroll
      for (int i = 0; i < 8; ++i) {
        v8[i] = s * SO[(g * 8 + i) * 68 + pos];
        pm = fmaxf(pm, v8[i]);
      }
      red[g * 64 + pos] = pm;
      __syncthreads();
      float m_ = fmaxf(fmaxf(red[pos], red[64 + pos]),
                       fmaxf(red[128 + pos], red[192 + pos]));
      __syncthreads();
      float ps = 0.f;
#pragma unroll
      for (int i = 0; i < 8; ++i) {
        v8[i] = __expf(v8[i] - m_);
        ps += v8[i];
      }
      red[g * 64 + pos] = ps;
      __syncthreads();
      float inv = 1.f / (red[pos] + red[64 + pos] + red[128 + pos] +
                         red[192 + pos]);
#pragma unroll
      for (int i = 0; i < 8; i += 2) {
        uint pk = (uint)f2bf(v8[i] * inv) | ((uint)f2bf(v8[i + 1] * inv) << 16);
        *(uint*)(&Pt[pos * 40 + g * 8 + i]) = pk;
      }
    }
    __syncthreads();
    // O = Pt(64x32) . svs^T : M=64(pos), N=64(d), K=32(f)
    {
      bf16x8 b_ = *(const bf16x8*)(&svs[(wv * 16 + l15) * 40 + kq * 8]);
      f32x4 acc3[4];
#pragma unroll
      for (int mt = 0; mt < 4; ++mt) {
        bf16x8 a_ = *(const bf16x8*)(&Pt[(mt * 16 + l15) * 40 + kq * 8]);
        f32x4 z = {0.f, 0.f, 0.f, 0.f};
        acc3[mt] = __builtin_amdgcn_mfma_f32_16x16x32_bf16(a_, b_, z, 0, 0, 0);
      }
#pragma unroll
      for (int mt = 0; mt < 4; ++mt)
#pragma unroll
        for (int r = 0; r < 4; ++r)
          SO[(mt * 16 + kq * 4 + r) * 68 + wv * 16 + l15] = acc3[mt][r];
    }
    __syncthreads();
    // OAT write (coalesced bf16x8)
#pragma unroll
    for (int it = 0; it < 2; ++it) {
      int lin = it * 256 + tid;
      int p = lin >> 3, c8 = lin & 7;
      ushort tmp[8];
#pragma unroll
      for (int j = 0; j < 8; ++j) tmp[j] = f2bf(SO[p * 68 + c8 * 8 + j]);
      *(uint4*)(&OAT[((size_t)b * Pc + pos0 + p) * INNERc + h * 64 + c8 * 8]) =
          *(const uint4*)tmp;
    }
    __syncthreads();
  }
}

// ---------------------------------------------------------------------------
// 8. Final GEMM: out = WoT . OAT + bias + s*res. K=512.
// ---------------------------------------------------------------------------
__global__ __launch_bounds__(256) void gemm_mfma_kernel(
    const ushort* __restrict__ A, const ushort* __restrict__ Bt,
    float* __restrict__ Out, int K, int Mdim,
    const float* __restrict__ bias, const float* __restrict__ res,
    const float* __restrict__ scale_p) {
  int b = blockIdx.z;
  int n0 = blockIdx.x * 128, m0 = blockIdx.y * 64;
  int tid = threadIdx.x, lane = tid & 63, wv = tid >> 6;
  int l15 = lane & 15, kq = lane >> 4;
  __shared__ alignas(16) ushort As[64 * 64];
  __shared__ alignas(16) ushort Bs[128 * 64];
  const ushort* Ab = A + (size_t)m0 * K;
  const ushort* Bb = Bt + ((size_t)b * Pc + n0) * K;

  f32x4 acc[4][2] = {};
  for (int k0 = 0; k0 < K; k0 += 64) {
#pragma unroll
    for (int it = 0; it < 2; ++it) {
      int lin = it * 256 + tid;
      int row = lin >> 3, p = lin & 7;
      int lc = p ^ (row & 7);
      *(uint4*)(&As[row * 64 + p * 8]) =
          *(const uint4*)(Ab + (size_t)row * K + k0 + lc * 8);
    }
#pragma unroll
    for (int it = 0; it < 4; ++it) {
      int lin = it * 256 + tid;
      int row = lin >> 3, p = lin & 7;
      int lc = p ^ (row & 7);
      *(uint4*)(&Bs[row * 64 + p * 8]) =
          *(const uint4*)(Bb + (size_t)row * K + k0 + lc * 8);
    }
    __syncthreads();
#pragma unroll
    for (int ss = 0; ss < 2; ++ss) {
      bf16x8 af[4], bfr[2];
#pragma unroll
      for (int mt = 0; mt < 4; ++mt) {
        int m = mt * 16 + l15;
        int p = (ss * 4 + kq) ^ (m & 7);
        af[mt] = *(const bf16x8*)(&As[m * 64 + p * 8]);
      }
#pragma unroll
      for (int nt = 0; nt < 2; ++nt) {
        int n = wv * 32 + nt * 16 + l15;
        int p = (ss * 4 + kq) ^ (n & 7);
        bfr[nt] = *(const bf16x8*)(&Bs[n * 64 + p * 8]);
      }
#pragma unroll
      for (int mt = 0; mt < 4; ++mt)
#pragma unroll
        for (int nt = 0; nt < 2; ++nt)
          acc[mt][nt] = __builtin_amdgcn_mfma_f32_16x16x32_bf16(
              af[mt], bfr[nt], acc[mt][nt], 0, 0, 0);
    }
    __syncthreads();
  }
  float s = scale_p[0];
  float* Ob = Out + ((size_t)b * Mdim + m0) * Pc + n0;
  const float* rb = res + ((size_t)b * Mdim + m0) * Pc + n0;
#pragma unroll
  for (int mt = 0; mt < 4; ++mt)
#pragma unroll
    for (int nt = 0; nt < 2; ++nt) {
      int ncol = wv * 32 + nt * 16 + l15;
#pragma unroll
      for (int r = 0; r < 4; ++r) {
        int m = mt * 16 + kq * 4 + r;
        Ob[(size_t)m * Pc + ncol] =
            acc[mt][nt][r] + bias[m0 + m] + s * rb[(size_t)m * Pc + ncol];
      }
    }
}

// ---------------------------------------------------------------------------
extern "C" void kernel_launch(void* const* d_in, const int* in_sizes, int n_in,
                              void* d_out, int out_size, void* d_ws, size_t ws_size,
                              hipStream_t stream) {
  const float* hs    = (const float*)d_in[0];
  const float* ehs   = (const float*)d_in[1];
  const float* Wq    = (const float*)d_in[2];
  const float* Wk    = (const float*)d_in[3];
  const float* Wv    = (const float*)d_in[4];
  const float* Wo    = (const float*)d_in[5];
  const float* bo    = (const float*)d_in[6];
  const float* gamma = (const float*)d_in[7];
  const float* beta  = (const float*)d_in[8];
  const float* exf   = (const float*)d_in[9];
  const float* dif   = (const float*)d_in[10];
  const float* scale = (const float*)d_in[11];
  float* out = (float*)d_out;

  float* ws = (float*)d_ws;
  float* svp  = ws;                        //   589,824 f (18*16*2048)
  float* mj   = svp + 589824;              //     9,216 f
  float* lj   = mj + 9216;                 //     9,216 f
  float* mu   = lj + 9216;                 //     4,608 f
  float* rstd = mu + 4608;                 //     4,608 f
  ushort* hsT  = (ushort*)(rstd + 4608);   // 1,474,560 us
  ushort* ehsT = hsT + 1474560;            // 1,474,560 us
  ushort* WvT  = ehsT + 1474560;           //   163,840 us
  ushort* WoT  = WvT + 163840;             //   163,840 us
  ushort* Gk   = WoT + 163840;             //    81,920 us
  ushort* Gq   = Gk + 81920;               //    81,920 us
  ushort* svT  = Gq + 81920;               //    32,768 us
  ushort* Vt   = svT + 32768;              // 2,359,296 us
  ushort* OAT  = Vt + 2359296;             // 2,359,296 us

  stats_kernel<<<dim3((Bc * Pc) / 64), dim3(256), 0, stream>>>(ehs, mu, rstd);
  transpose_act_kernel<<<dim3(Pc / 64, Cc / 64, 4), dim3(256), 0, stream>>>(
      hs, ehs, mu, rstd, gamma, beta, hsT, ehsT);
  prep_w_kernel<<<dim3(160), dim3(256), 0, stream>>>(
      Wv, Wo, exf, Wk, dif, Wq, WvT, WoT, Gk, Gq);
  gemm_v_kernel<<<dim3(Pc / 128, INNERc / 64, Bc), dim3(256), 0, stream>>>(
      WvT, ehsT, Vt);
  spatial_kernel<<<dim3(CHUNKS, HEADSc, Bc), dim3(256), 0, stream>>>(
      Gk, ehsT, Vt, scale, svp, mj, lj);
  sv_reduce_kernel<<<dim3(128), dim3(256), 0, stream>>>(svp, mj, lj, svT);
  channel_kernel<<<dim3(Pc / 64, HEADSc / 2, Bc), dim3(256), 0, stream>>>(
      Gq, hsT, svT, scale, OAT);
  gemm_mfma_kernel<<<dim3(Pc / 128, Cc / 64, Bc), dim3(256), 0, stream>>>(
      WoT, OAT, out, INNERc, Cc, bo, hs, scale);
}

// Round 7
// 138.366 us; speedup vs baseline: 3.5105x; 1.1265x over previous
//
#include <hip/hip_runtime.h>
#include <math.h>

#define Bc 2
#define Cc 320
#define Pc 2304
#define HEADSc 8
#define DHc 64
#define INNERc 512
#define Fc 32
#define LN_EPS 1e-5f
#define CHUNKS 18
#define CHUNK_P 128

typedef __attribute__((ext_vector_type(8))) short bf16x8;
typedef __attribute__((ext_vector_type(4))) float f32x4;

static __device__ __forceinline__ ushort f2bf(float x) {
  uint u = __builtin_bit_cast(uint, x);
  u = (u + 0x7fffu + ((u >> 16) & 1u)) >> 16;
  return (ushort)u;
}

// ---------------------------------------------------------------------------
// Transpose+cast tile helper: src fp32 [R][C] -> dst bf16 [C][R]; 64x64
// ---------------------------------------------------------------------------
static __device__ void transpose_tile(const float* __restrict__ src,
                                      ushort* __restrict__ dst, int R, int C,
                                      int r0, int c0, int tid,
                                      float (*t)[65]) {
#pragma unroll
  for (int it = 0; it < 4; ++it) {
    int lin = it * 256 + tid;
    int rr = lin >> 4, c4 = lin & 15;
    float4 v = *(const float4*)(&src[(size_t)(r0 + rr) * C + c0 + c4 * 4]);
    t[rr][c4 * 4 + 0] = v.x; t[rr][c4 * 4 + 1] = v.y;
    t[rr][c4 * 4 + 2] = v.z; t[rr][c4 * 4 + 3] = v.w;
  }
  __syncthreads();
#pragma unroll
  for (int it = 0; it < 2; ++it) {
    int lin = it * 256 + tid;
    int cc = lin >> 3, r8 = lin & 7;
    ushort tmp[8];
#pragma unroll
    for (int j = 0; j < 8; ++j) tmp[j] = f2bf(t[r8 * 8 + j][cc]);
    *(uint4*)(&dst[(size_t)(c0 + cc) * R + r0 + r8 * 8]) = *(const uint4*)tmp;
  }
}

// ---------------------------------------------------------------------------
// 1. ALL prep in one launch (304 blocks):
//    [0,144): activation transpose+cast, LN fused for ehs path.
//             i%36 = pos-tile, i/36 = b + 2*which
//    [144,184): WvT transpose   [184,224): WoT transpose
//    [224,304): gfuse Gk/Gq
// ---------------------------------------------------------------------------
__global__ __launch_bounds__(256) void prep_all_kernel(
    const float* __restrict__ hs, const float* __restrict__ ehs,
    const float* __restrict__ gamma, const float* __restrict__ beta,
    const float* __restrict__ Wv, const float* __restrict__ Wo,
    const float* __restrict__ exf, const float* __restrict__ Wk,
    const float* __restrict__ dif, const float* __restrict__ Wq,
    ushort* __restrict__ hsT, ushort* __restrict__ ehsT,
    ushort* __restrict__ WvT, ushort* __restrict__ WoT,
    ushort* __restrict__ Gk, ushort* __restrict__ Gq) {
  __shared__ float smem[6448];
  int idx = blockIdx.x, tid = threadIdx.x;

  if (idx < 144) {
    // ---- activation path: 64 positions x all 320 channels
    int pt = idx % 36, z = idx / 36;
    int b = z & 1, which = z >> 1;
    int pos0 = pt * 64;
    const float* src = (which ? ehs : hs) + (size_t)b * Cc * Pc;
    ushort* dst = (which ? ehsT : hsT) + (size_t)b * Pc * Cc;
    float* t = smem;               // [64][65] = 4160
    float* s1 = smem + 4160;       // [4][64]
    float* s2 = smem + 4416;
    float* lmean = smem + 4672;    // [64]
    float* lrstd = smem + 4736;    // [64]
    int lane = tid & 63, g = tid >> 6;
    if (which) {
      const float* base = src + pos0 + lane;
      float sum = 0.f, sq = 0.f;
      for (int c = g * 80; c < g * 80 + 80; ++c) {
        float x = base[(size_t)c * Pc];
        sum += x; sq += x * x;
      }
      s1[g * 64 + lane] = sum; s2[g * 64 + lane] = sq;
      __syncthreads();
      if (tid < 64) {
        float ts = s1[tid] + s1[64 + tid] + s1[128 + tid] + s1[192 + tid];
        float tq = s2[tid] + s2[64 + tid] + s2[128 + tid] + s2[192 + tid];
        float mean = ts / (float)Cc;
        float var = tq / (float)Cc - mean * mean;
        lmean[tid] = mean;
        lrstd[tid] = rsqrtf(var + LN_EPS);
      }
      __syncthreads();
    }
    for (int ct = 0; ct < 5; ++ct) {
      int r0 = ct * 64;
#pragma unroll
      for (int it = 0; it < 4; ++it) {
        int lin = it * 256 + tid;
        int rr = lin >> 4, c4 = lin & 15;
        float4 v = *(const float4*)(&src[(size_t)(r0 + rr) * Pc + pos0 + c4 * 4]);
        t[rr * 65 + c4 * 4 + 0] = v.x; t[rr * 65 + c4 * 4 + 1] = v.y;
        t[rr * 65 + c4 * 4 + 2] = v.z; t[rr * 65 + c4 * 4 + 3] = v.w;
      }
      __syncthreads();
#pragma unroll
      for (int it = 0; it < 2; ++it) {
        int lin = it * 256 + tid;
        int cc = lin >> 3, r8 = lin & 7;
        float m_ = which ? lmean[cc] : 0.f, rs_ = which ? lrstd[cc] : 1.f;
        ushort tmp[8];
#pragma unroll
        for (int j = 0; j < 8; ++j) {
          int ch = r8 * 8 + j;
          float x = t[ch * 65 + cc];
          float val = which ? (x - m_) * rs_ * gamma[r0 + ch] + beta[r0 + ch] : x;
          tmp[j] = f2bf(val);
        }
        *(uint4*)(&dst[(size_t)(pos0 + cc) * Cc + r0 + r8 * 8]) =
            *(const uint4*)tmp;
      }
      __syncthreads();
    }
  } else {
    int idx2 = idx - 144;
    if (idx2 < 40) {
      transpose_tile(Wv, WvT, Cc, INNERc, (idx2 / 8) * 64, (idx2 % 8) * 64,
                     tid, (float(*)[65])smem);
    } else if (idx2 < 80) {
      int i = idx2 - 40;
      transpose_tile(Wo, WoT, INNERc, Cc, (i / 5) * 64, (i % 5) * 64, tid,
                     (float(*)[65])smem);
    } else {
      int i = idx2 - 80;
      int c0 = (i % 5) * 64, h = (i / 5) % 8, zz = i / 40;
      const float* filt = zz ? dif : exf;
      const float* W = zz ? Wq : Wk;
      ushort* G = zz ? Gq : Gk;
      float (*ef)[66] = (float(*)[66])smem;
      float (*wk)[65] = (float(*)[65])(smem + 32 * 66);
      for (int l = tid; l < Fc * DHc; l += 256) {
        int f = l >> 6, d = l & 63;
        ef[f][d] = filt[(size_t)f * INNERc + h * 64 + d];
      }
      for (int l = tid; l < 64 * DHc; l += 256) {
        int cc = l >> 6, d = l & 63;
        wk[cc][d] = W[(size_t)(c0 + cc) * INNERc + h * 64 + d];
      }
      __syncthreads();
      int f = tid >> 3, cbase = tid & 7;
      float acc[8] = {};
#pragma unroll
      for (int d4 = 0; d4 < DHc; d4 += 4) {
        float4 a = *(const float4*)(&ef[f][d4]);
#pragma unroll
        for (int j = 0; j < 8; ++j) {
          float4 b = *(const float4*)(&wk[cbase + j * 8][d4]);
          acc[j] += a.x * b.x + a.y * b.y + a.z * b.z + a.w * b.w;
        }
      }
#pragma unroll
      for (int j = 0; j < 8; ++j)
        G[(size_t)(h * Fc + f) * Cc + c0 + cbase + j * 8] = f2bf(acc[j]);
    }
  }
}

// ---------------------------------------------------------------------------
// 2. Fused spatial attention chunk with V-projection fused in (no global V):
//    One K-loop computes [V(64 rows) ; S(32 rows)] = [WvT_h ; Gk_h] . ehsT^T
//    V -> LDS bf16; local softmax of S; O_j = P . V^T (MFMA).
// ---------------------------------------------------------------------------
__global__ __launch_bounds__(256) void spatial_kernel(
    const ushort* __restrict__ Gk, const ushort* __restrict__ ehsT,
    const ushort* __restrict__ WvT, const float* __restrict__ scale_p,
    float* __restrict__ svp, float* __restrict__ mj, float* __restrict__ lj) {
  int c = blockIdx.x, h = blockIdx.y, b = blockIdx.z;
  int tid = threadIdx.x, lane = tid & 63, wv = tid >> 6;
  int l15 = lane & 15, kq = lane >> 4;
  int pos0 = c * CHUNK_P;
  int bh = b * HEADSc + h;
  float s = scale_p[0];

  __shared__ alignas(16) ushort As[96 * 64];    // rows 0-63: WvT_h, 64-95: Gk_h
  __shared__ alignas(16) ushort Bs[128 * 64];   // ehsT k-tile
  __shared__ float Sq[32 * 132];                // scores fp32
  __shared__ alignas(16) ushort P[32 * 136];    // exp numerator bf16
  __shared__ alignas(16) ushort Vs[64 * 136];   // V chunk [d][pos] bf16

  const ushort* Av = WvT + (size_t)(h * 64) * Cc;
  const ushort* Ag = Gk + (size_t)(h * Fc) * Cc;
  const ushort* Bb = ehsT + ((size_t)b * Pc + pos0) * Cc;

  f32x4 acc[6][2] = {};
  for (int k0 = 0; k0 < Cc; k0 += 64) {
#pragma unroll
    for (int it = 0; it < 3; ++it) {
      int lin = it * 256 + tid;       // 768 chunks: 96 rows x 8
      int row = lin >> 3, p = lin & 7;
      int lc = p ^ (row & 7);
      const ushort* sp = (row < 64) ? (Av + (size_t)row * Cc + k0 + lc * 8)
                                    : (Ag + (size_t)(row - 64) * Cc + k0 + lc * 8);
      *(uint4*)(&As[row * 64 + p * 8]) = *(const uint4*)sp;
    }
#pragma unroll
    for (int it = 0; it < 4; ++it) {
      int lin = it * 256 + tid;       // 1024 chunks: 128 rows x 8
      int row = lin >> 3, p = lin & 7;
      int lc = p ^ (row & 7);
      *(uint4*)(&Bs[row * 64 + p * 8]) =
          *(const uint4*)(Bb + (size_t)row * Cc + k0 + lc * 8);
    }
    __syncthreads();
#pragma unroll
    for (int ss = 0; ss < 2; ++ss) {
      bf16x8 af[6], bfr[2];
#pragma unroll
      for (int mt = 0; mt < 6; ++mt) {
        int m = mt * 16 + l15;
        int p = (ss * 4 + kq) ^ (m & 7);
        af[mt] = *(const bf16x8*)(&As[m * 64 + p * 8]);
      }
#pragma unroll
      for (int nt = 0; nt < 2; ++nt) {
        int n = wv * 32 + nt * 16 + l15;
        int p = (ss * 4 + kq) ^ (n & 7);
        bfr[nt] = *(const bf16x8*)(&Bs[n * 64 + p * 8]);
      }
#pragma unroll
      for (int mt = 0; mt < 6; ++mt)
#pragma unroll
        for (int nt = 0; nt < 2; ++nt)
          acc[mt][nt] = __builtin_amdgcn_mfma_f32_16x16x32_bf16(
              af[mt], bfr[nt], acc[mt][nt], 0, 0, 0);
    }
    __syncthreads();
  }
  // scatter: mt<4 -> Vs (bf16), mt 4..5 -> Sq (fp32)
#pragma unroll
  for (int mt = 0; mt < 6; ++mt)
#pragma unroll
    for (int nt = 0; nt < 2; ++nt) {
      int col = wv * 32 + nt * 16 + l15;
#pragma unroll
      for (int r = 0; r < 4; ++r) {
        int row = mt * 16 + kq * 4 + r;
        if (mt < 4) Vs[row * 136 + col] = f2bf(acc[mt][nt][r]);
        else Sq[(row - 64) * 132 + col] = acc[mt][nt][r];
      }
    }
  __syncthreads();

  // per-row (f) local max + exp-sum; P = exp(s*S - m)
  {
    int row = tid >> 3, sub = tid & 7;
    float vals[16];
    float m_ = -1e30f;
#pragma unroll
    for (int i = 0; i < 16; ++i) {
      vals[i] = s * Sq[row * 132 + sub * 16 + i];
      m_ = fmaxf(m_, vals[i]);
    }
    m_ = fmaxf(m_, __shfl_xor(m_, 1));
    m_ = fmaxf(m_, __shfl_xor(m_, 2));
    m_ = fmaxf(m_, __shfl_xor(m_, 4));
    float l_ = 0.f;
#pragma unroll
    for (int i = 0; i < 16; i += 2) {
      float e0 = __expf(vals[i] - m_);
      float e1 = __expf(vals[i + 1] - m_);
      l_ += e0 + e1;
      uint pk = (uint)f2bf(e0) | ((uint)f2bf(e1) << 16);
      *(uint*)(&P[row * 136 + sub * 16 + i]) = pk;
    }
    l_ += __shfl_xor(l_, 1);
    l_ += __shfl_xor(l_, 2);
    l_ += __shfl_xor(l_, 4);
    if (sub == 0) {
      mj[((size_t)c * 16 + bh) * Fc + row] = m_;
      lj[((size_t)c * 16 + bh) * Fc + row] = l_;
    }
  }
  __syncthreads();

  // O = P(32x128) . V^T  (M=32, N=64, K=128)
  f32x4 acc2[2] = {};
#pragma unroll
  for (int ss = 0; ss < 4; ++ss) {
    bf16x8 af[2];
#pragma unroll
    for (int mt = 0; mt < 2; ++mt)
      af[mt] = *(const bf16x8*)(&P[(mt * 16 + l15) * 136 + ss * 32 + kq * 8]);
    bf16x8 bfr = *(const bf16x8*)(&Vs[(wv * 16 + l15) * 136 + ss * 32 + kq * 8]);
#pragma unroll
    for (int mt = 0; mt < 2; ++mt)
      acc2[mt] = __builtin_amdgcn_mfma_f32_16x16x32_bf16(af[mt], bfr, acc2[mt],
                                                         0, 0, 0);
  }
  float* op = svp + ((size_t)c * 16 + bh) * (Fc * DHc);
#pragma unroll
  for (int mt = 0; mt < 2; ++mt)
#pragma unroll
    for (int r = 0; r < 4; ++r)
      op[(mt * 16 + kq * 4 + r) * DHc + wv * 16 + l15] = acc2[mt][r];
}

// ---------------------------------------------------------------------------
// 3. Online-softmax reduce of 18 chunks -> svT[bh][d][f] bf16
// ---------------------------------------------------------------------------
__global__ __launch_bounds__(256) void sv_reduce_kernel(
    const float* __restrict__ svp, const float* __restrict__ mj,
    const float* __restrict__ lj, ushort* __restrict__ svT) {
  int idx = blockIdx.x * 256 + threadIdx.x;  // 32768
  int d = idx & 63, fr = idx >> 6;
  int bh = fr >> 5, f = fr & 31;
  float m = -1e30f;
#pragma unroll
  for (int c = 0; c < CHUNKS; ++c)
    m = fmaxf(m, mj[((size_t)c * 16 + bh) * Fc + f]);
  float osum = 0.f, lsum = 0.f;
#pragma unroll
  for (int c = 0; c < CHUNKS; ++c) {
    float w = __expf(mj[((size_t)c * 16 + bh) * Fc + f] - m);
    osum += w * svp[((size_t)c * 16 + bh) * (Fc * DHc) + f * DHc + d];
    lsum += w * lj[((size_t)c * 16 + bh) * Fc + f];
  }
  svT[((size_t)bh * DHc + d) * Fc + f] = f2bf(osum / lsum);
}

// ---------------------------------------------------------------------------
// 4. Fused channel attention -> OAT[b][pos][h*64+d] bf16
// ---------------------------------------------------------------------------
__global__ __launch_bounds__(256) void channel_kernel(
    const ushort* __restrict__ Gq, const ushort* __restrict__ hsT,
    const ushort* __restrict__ svT, const float* __restrict__ scale_p,
    ushort* __restrict__ OAT) {
  int pb = blockIdx.x, hp = blockIdx.y, b = blockIdx.z;
  int pos0 = pb * 64;
  int tid = threadIdx.x, lane = tid & 63, wv = tid >> 6;
  int l15 = lane & 15, kq = lane >> 4;
  float s = scale_p[0];

  __shared__ alignas(16) ushort Aq[2][32 * 64];
  __shared__ alignas(16) ushort Bs[64 * 64];
  __shared__ float SO[64 * 68];
  __shared__ alignas(16) ushort Pt[64 * 40];
  __shared__ alignas(16) ushort svs[64 * 40];
  __shared__ float red[4 * 64];

  f32x4 acc[2][2] = {};
  const ushort* Bb = hsT + ((size_t)b * Pc + pos0) * Cc;
  for (int k0 = 0; k0 < Cc; k0 += 64) {
#pragma unroll
    for (int it = 0; it < 2; ++it) {
      int lin = it * 256 + tid;
      int hh = lin >> 8, row = (lin >> 3) & 31, p = lin & 7;
      int lc = p ^ (row & 7);
      *(uint4*)(&Aq[hh][row * 64 + p * 8]) = *(const uint4*)(
          Gq + (size_t)((hp * 2 + hh) * Fc + row) * Cc + k0 + lc * 8);
    }
#pragma unroll
    for (int it = 0; it < 2; ++it) {
      int lin = it * 256 + tid;
      int row = lin >> 3, p = lin & 7;
      int lc = p ^ (row & 7);
      *(uint4*)(&Bs[row * 64 + p * 8]) =
          *(const uint4*)(Bb + (size_t)row * Cc + k0 + lc * 8);
    }
    __syncthreads();
#pragma unroll
    for (int ss = 0; ss < 2; ++ss) {
      int n = wv * 16 + l15;
      int pb_ = (ss * 4 + kq) ^ (n & 7);
      bf16x8 bfr = *(const bf16x8*)(&Bs[n * 64 + pb_ * 8]);
#pragma unroll
      for (int hh = 0; hh < 2; ++hh)
#pragma unroll
        for (int mt = 0; mt < 2; ++mt) {
          int m = mt * 16 + l15;
          int pa = (ss * 4 + kq) ^ (m & 7);
          bf16x8 af = *(const bf16x8*)(&Aq[hh][m * 64 + pa * 8]);
          acc[hh][mt] = __builtin_amdgcn_mfma_f32_16x16x32_bf16(
              af, bfr, acc[hh][mt], 0, 0, 0);
        }
    }
    __syncthreads();
  }

  for (int hh = 0; hh < 2; ++hh) {
    int h = hp * 2 + hh;
#pragma unroll
    for (int mt = 0; mt < 2; ++mt)
#pragma unroll
      for (int r = 0; r < 4; ++r)
        SO[(mt * 16 + kq * 4 + r) * 68 + wv * 16 + l15] = acc[hh][mt][r];
    {
      int rr = tid >> 2, p = tid & 3;
      *(uint4*)(&svs[rr * 40 + p * 8]) = *(const uint4*)(
          svT + ((size_t)(b * HEADSc + h) * DHc + rr) * Fc + p * 8);
    }
    __syncthreads();
    {
      int pos = tid & 63, g = tid >> 6;
      float v8[8];
      float pm = -1e30f;
#pragma unroll
      for (int i = 0; i < 8; ++i) {
        v8[i] = s * SO[(g * 8 + i) * 68 + pos];
        pm = fmaxf(pm, v8[i]);
      }
      red[g * 64 + pos] = pm;
      __syncthreads();
      float m_ = fmaxf(fmaxf(red[pos], red[64 + pos]),
                       fmaxf(red[128 + pos], red[192 + pos]));
      __syncthreads();
      float ps = 0.f;
#pragma unroll
      for (int i = 0; i < 8; ++i) {
        v8[i] = __expf(v8[i] - m_);
        ps += v8[i];
      }
      red[g * 64 + pos] = ps;
      __syncthreads();
      float inv = 1.f / (red[pos] + red[64 + pos] + red[128 + pos] +
                         red[192 + pos]);
#pragma unroll
      for (int i = 0; i < 8; i += 2) {
        uint pk = (uint)f2bf(v8[i] * inv) | ((uint)f2bf(v8[i + 1] * inv) << 16);
        *(uint*)(&Pt[pos * 40 + g * 8 + i]) = pk;
      }
    }
    __syncthreads();
    {
      bf16x8 b_ = *(const bf16x8*)(&svs[(wv * 16 + l15) * 40 + kq * 8]);
      f32x4 acc3[4];
#pragma unroll
      for (int mt = 0; mt < 4; ++mt) {
        bf16x8 a_ = *(const bf16x8*)(&Pt[(mt * 16 + l15) * 40 + kq * 8]);
        f32x4 z = {0.f, 0.f, 0.f, 0.f};
        acc3[mt] = __builtin_amdgcn_mfma_f32_16x16x32_bf16(a_, b_, z, 0, 0, 0);
      }
#pragma unroll
      for (int mt = 0; mt < 4; ++mt)
#pragma unroll
        for (int r = 0; r < 4; ++r)
          SO[(mt * 16 + kq * 4 + r) * 68 + wv * 16 + l15] = acc3[mt][r];
    }
    __syncthreads();
#pragma unroll
    for (int it = 0; it < 2; ++it) {
      int lin = it * 256 + tid;
      int p = lin >> 3, c8 = lin & 7;
      ushort tmp[8];
#pragma unroll
      for (int j = 0; j < 8; ++j) tmp[j] = f2bf(SO[p * 68 + c8 * 8 + j]);
      *(uint4*)(&OAT[((size_t)b * Pc + pos0 + p) * INNERc + h * 64 + c8 * 8]) =
          *(const uint4*)tmp;
    }
    __syncthreads();
  }
}

// ---------------------------------------------------------------------------
// 5. Final GEMM: out = WoT . OAT + bias + s*res. K=512.
// ---------------------------------------------------------------------------
__global__ __launch_bounds__(256) void gemm_mfma_kernel(
    const ushort* __restrict__ A, const ushort* __restrict__ Bt,
    float* __restrict__ Out, int K, int Mdim,
    const float* __restrict__ bias, const float* __restrict__ res,
    const float* __restrict__ scale_p) {
  int b = blockIdx.z;
  int n0 = blockIdx.x * 128, m0 = blockIdx.y * 64;
  int tid = threadIdx.x, lane = tid & 63, wv = tid >> 6;
  int l15 = lane & 15, kq = lane >> 4;
  __shared__ alignas(16) ushort As[64 * 64];
  __shared__ alignas(16) ushort Bs[128 * 64];
  const ushort* Ab = A + (size_t)m0 * K;
  const ushort* Bb = Bt + ((size_t)b * Pc + n0) * K;

  f32x4 acc[4][2] = {};
  for (int k0 = 0; k0 < K; k0 += 64) {
#pragma unroll
    for (int it = 0; it < 2; ++it) {
      int lin = it * 256 + tid;
      int row = lin >> 3, p = lin & 7;
      int lc = p ^ (row & 7);
      *(uint4*)(&As[row * 64 + p * 8]) =
          *(const uint4*)(Ab + (size_t)row * K + k0 + lc * 8);
    }
#pragma unroll
    for (int it = 0; it < 4; ++it) {
      int lin = it * 256 + tid;
      int row = lin >> 3, p = lin & 7;
      int lc = p ^ (row & 7);
      *(uint4*)(&Bs[row * 64 + p * 8]) =
          *(const uint4*)(Bb + (size_t)row * K + k0 + lc * 8);
    }
    __syncthreads();
#pragma unroll
    for (int ss = 0; ss < 2; ++ss) {
      bf16x8 af[4], bfr[2];
#pragma unroll
      for (int mt = 0; mt < 4; ++mt) {
        int m = mt * 16 + l15;
        int p = (ss * 4 + kq) ^ (m & 7);
        af[mt] = *(const bf16x8*)(&As[m * 64 + p * 8]);
      }
#pragma unroll
      for (int nt = 0; nt < 2; ++nt) {
        int n = wv * 32 + nt * 16 + l15;
        int p = (ss * 4 + kq) ^ (n & 7);
        bfr[nt] = *(const bf16x8*)(&Bs[n * 64 + p * 8]);
      }
#pragma unroll
      for (int mt = 0; mt < 4; ++mt)
#pragma unroll
        for (int nt = 0; nt < 2; ++nt)
          acc[mt][nt] = __builtin_amdgcn_mfma_f32_16x16x32_bf16(
              af[mt], bfr[nt], acc[mt][nt], 0, 0, 0);
    }
    __syncthreads();
  }
  float s = scale_p[0];
  float* Ob = Out + ((size_t)b * Mdim + m0) * Pc + n0;
  const float* rb = res + ((size_t)b * Mdim + m0) * Pc + n0;
#pragma unroll
  for (int mt = 0; mt < 4; ++mt)
#pragma unroll
    for (int nt = 0; nt < 2; ++nt) {
      int ncol = wv * 32 + nt * 16 + l15;
#pragma unroll
      for (int r = 0; r < 4; ++r) {
        int m = mt * 16 + kq * 4 + r;
        Ob[(size_t)m * Pc + ncol] =
            acc[mt][nt][r] + bias[m0 + m] + s * rb[(size_t)m * Pc + ncol];
      }
    }
}

// ---------------------------------------------------------------------------
extern "C" void kernel_launch(void* const* d_in, const int* in_sizes, int n_in,
                              void* d_out, int out_size, void* d_ws, size_t ws_size,
                              hipStream_t stream) {
  const float* hs    = (const float*)d_in[0];
  const float* ehs   = (const float*)d_in[1];
  const float* Wq    = (const float*)d_in[2];
  const float* Wk    = (const float*)d_in[3];
  const float* Wv    = (const float*)d_in[4];
  const float* Wo    = (const float*)d_in[5];
  const float* bo    = (const float*)d_in[6];
  const float* gamma = (const float*)d_in[7];
  const float* beta  = (const float*)d_in[8];
  const float* exf   = (const float*)d_in[9];
  const float* dif   = (const float*)d_in[10];
  const float* scale = (const float*)d_in[11];
  float* out = (float*)d_out;

  float* ws = (float*)d_ws;
  float* svp = ws;                         //   589,824 f
  float* mj  = svp + 589824;               //     9,216 f
  float* lj  = mj + 9216;                  //     9,216 f
  ushort* hsT  = (ushort*)(lj + 9216);     // 1,474,560 us
  ushort* ehsT = hsT + 1474560;            // 1,474,560 us
  ushort* WvT  = ehsT + 1474560;           //   163,840 us
  ushort* WoT  = WvT + 163840;             //   163,840 us
  ushort* Gk   = WoT + 163840;             //    81,920 us
  ushort* Gq   = Gk + 81920;               //    81,920 us
  ushort* svT  = Gq + 81920;               //    32,768 us
  ushort* OAT  = svT + 32768;              // 2,359,296 us

  prep_all_kernel<<<dim3(304), dim3(256), 0, stream>>>(
      hs, ehs, gamma, beta, Wv, Wo, exf, Wk, dif, Wq,
      hsT, ehsT, WvT, WoT, Gk, Gq);
  spatial_kernel<<<dim3(CHUNKS, HEADSc, Bc), dim3(256), 0, stream>>>(
      Gk, ehsT, WvT, scale, svp, mj, lj);
  sv_reduce_kernel<<<dim3(128), dim3(256), 0, stream>>>(svp, mj, lj, svT);
  channel_kernel<<<dim3(Pc / 64, HEADSc / 2, Bc), dim3(256), 0, stream>>>(
      Gq, hsT, svT, scale, OAT);
  gemm_mfma_kernel<<<dim3(Pc / 128, Cc / 64, Bc), dim3(256), 0, stream>>>(
      WoT, OAT, out, INNERc, Cc, bo, hs, scale);
}